// Round 5
// baseline (522.842 us; speedup 1.0000x reference)
//
#include <hip/hip_runtime.h>
#include <math.h>

// ---------------------------------------------------------------------------
// EMD layer (Sinkhorn-OT logits) for MI355X.
// support: [32,512,8,8] f32, query: [256,512,8,8] f32 -> logits [256,32] f32.
//
// R5: split emd at the occupancy boundary:
//   sim_kernel   (MFMA + exp + permuted transpose, 4 waves/EU, AGPR-bound)
//                -> stores fp16 Gibbs tiles Mg[p][t][lane*8] coalesced
//   skh_kernel   (one-wave blocks, no LDS, launch_bounds(64,8) -> 32 waves/CU)
//                -> 100-iter exp-domain Sinkhorn + logits
// Prep: norm 2-pass (pool fused via wave shfl-reduce), amarg/bmarg 8-deep
// prefetch. Workspace-size-adaptive Mg split (1/2/4) for safety.
// ---------------------------------------------------------------------------

#define DEV static __device__ __forceinline__

typedef _Float16 half8 __attribute__((ext_vector_type(8)));
typedef float floatx4 __attribute__((ext_vector_type(4)));

DEV float fast_rcp(float x) {
#if __has_builtin(__builtin_amdgcn_rcpf)
    return __builtin_amdgcn_rcpf(x);
#else
    return 1.0f / x;
#endif
}
DEV float fexp2(float x) {
#if __has_builtin(__builtin_amdgcn_exp2f)
    return __builtin_amdgcn_exp2f(x);
#else
    return exp2f(x);
#endif
}
DEV float flog2(float x) {
#if __has_builtin(__builtin_amdgcn_logf)
    return __builtin_amdgcn_logf(x);
#else
    return log2f(x);
#endif
}

#define K_SIM2M 28.853900817779268f    // 20/ln2 : M = 2^((sim-1)*K_SIM2M)
#define K_M2SIM 0.034657359027997264f  // 0.05*ln2 : sim = 1 + log2(M)*K_M2SIM
#define LDP 68                         // padded LDS row stride (floats)

// ------ K1: center+normalize over C -> fp16 node-major, + pooled means ------
// 2 passes over src. Pool = per-c mean over 64 nodes = wave shfl-reduce
// (the 64 lanes of a wave ARE the 64 nodes), fused into the stats pass.
__global__ void __launch_bounds__(256)
norm_kernel(const float* __restrict__ support, const float* __restrict__ query,
            _Float16* __restrict__ Vht, _Float16* __restrict__ Uht,
            float* __restrict__ BpT, float* __restrict__ QpT) {
    __shared__ float red1[4][64];
    __shared__ float red2[4][64];
    __shared__ float muL[64], invL[64];
    __shared__ float tile[128][65];

    int sid = blockIdx.x;             // 0..287
    const float* src;
    _Float16* dst;
    float* poolT;
    int pstride, pidx;
    if (sid < 32) {
        src = support + (size_t)sid * 32768; dst = Vht + (size_t)sid * 32768;
        poolT = BpT; pstride = 32; pidx = sid;
    } else {
        src = query + (size_t)(sid - 32) * 32768; dst = Uht + (size_t)(sid - 32) * 32768;
        poolT = QpT; pstride = 256; pidx = sid - 32;
    }

    int node = threadIdx.x & 63;
    int cq   = threadIdx.x >> 6;      // wave index = c-quarter

    float s1 = 0.f, s2 = 0.f;
#pragma unroll 8
    for (int j = 0; j < 128; ++j) {
        int c = cq * 128 + j;
        float x = src[c * 64 + node];
        s1 += x; s2 += x * x;
        float ps = x;                  // pool: sum over the wave's 64 nodes
        ps += __shfl_xor(ps, 1);  ps += __shfl_xor(ps, 2);  ps += __shfl_xor(ps, 4);
        ps += __shfl_xor(ps, 8);  ps += __shfl_xor(ps, 16); ps += __shfl_xor(ps, 32);
        if (node == 0) poolT[(size_t)c * pstride + pidx] = ps * (1.0f / 64.0f);
    }
    red1[cq][node] = s1;
    red2[cq][node] = s2;
    __syncthreads();
    if (threadIdx.x < 64) {
        float t1 = red1[0][node] + red1[1][node] + red1[2][node] + red1[3][node];
        float t2 = red2[0][node] + red2[1][node] + red2[2][node] + red2[3][node];
        float mu = t1 * (1.0f / 512.0f);
        float ss = t2 - 512.0f * mu * mu;
        muL[node]  = mu;
        invL[node] = 1.0f / fmaxf(sqrtf(fmaxf(ss, 0.0f)), 1e-8f);
    }
    __syncthreads();

    for (int ch = 0; ch < 4; ++ch) {
        float mu = muL[node], inv = invL[node];
#pragma unroll 4
        for (int j = 0; j < 32; ++j) {
            int cl = cq * 32 + j;
            float x = src[(ch * 128 + cl) * 64 + node];
            tile[cl][node] = (x - mu) * inv;
        }
        __syncthreads();
#pragma unroll
        for (int r = 0; r < 4; ++r) {
            int lin = r * 256 + threadIdx.x;
            int nd  = lin >> 4;
            int c8  = lin & 15;
            half8 v;
#pragma unroll
            for (int i = 0; i < 8; ++i) v[i] = (_Float16)tile[c8 * 8 + i][nd];
            *(half8*)(dst + (size_t)nd * 512 + ch * 128 + c8 * 8) = v;
        }
        __syncthreads();
    }
}

// --------- K2a: a-marginals with 8-deep load prefetch -----------------------
__global__ void __launch_bounds__(256)
amarg_kernel(const float* __restrict__ query, const float* __restrict__ BpT,
             float* __restrict__ a_out) {
    __shared__ __align__(16) float BpL[512 * 32];   // [c][w] 64 KB
    int q    = blockIdx.x;
    int lane = threadIdx.x & 63;   // node
    int wq   = threadIdx.x >> 6;   // w = wq*8 .. +7
    for (int t = threadIdx.x; t < 4096; t += 256)
        ((float4*)BpL)[t] = ((const float4*)BpT)[t];
    __syncthreads();
    float acc[8] = {0, 0, 0, 0, 0, 0, 0, 0};
    const float* qbase = query + (size_t)q * 32768 + lane;
#pragma unroll 1
    for (int c0 = 0; c0 < 512; c0 += 8) {
        float x[8];
#pragma unroll
        for (int j = 0; j < 8; ++j) x[j] = qbase[(size_t)(c0 + j) * 64];
#pragma unroll
        for (int j = 0; j < 8; ++j) {
            float4 b0 = *(const float4*)(BpL + (c0 + j) * 32 + wq * 8);
            float4 b1 = *(const float4*)(BpL + (c0 + j) * 32 + wq * 8 + 4);
            acc[0] = fmaf(x[j], b0.x, acc[0]); acc[1] = fmaf(x[j], b0.y, acc[1]);
            acc[2] = fmaf(x[j], b0.z, acc[2]); acc[3] = fmaf(x[j], b0.w, acc[3]);
            acc[4] = fmaf(x[j], b1.x, acc[4]); acc[5] = fmaf(x[j], b1.y, acc[5]);
            acc[6] = fmaf(x[j], b1.z, acc[6]); acc[7] = fmaf(x[j], b1.w, acc[7]);
        }
    }
#pragma unroll
    for (int k = 0; k < 8; ++k) {
        float v = fmaxf(acc[k], 0.0f) + 0.001f;
        v += 1e-5f;
        float s = v;
        s += __shfl_xor(s, 1);  s += __shfl_xor(s, 2);  s += __shfl_xor(s, 4);
        s += __shfl_xor(s, 8);  s += __shfl_xor(s, 16); s += __shfl_xor(s, 32);
        int w = wq * 8 + k;
        a_out[((size_t)q * 32 + w) * 64 + lane] = v * (64.0f / s);
    }
}

// --------- K2b: b-marginals with 8-deep load prefetch -----------------------
__global__ void __launch_bounds__(256)
bmarg_kernel(const float* __restrict__ support, const float* __restrict__ QpT,
             float* __restrict__ b_out) {
    __shared__ __align__(16) float QpL[512 * 32];   // [c][qlocal] 64 KB
    int w    = blockIdx.x >> 3;
    int qg   = blockIdx.x & 7;     // q base qg*32
    int lane = threadIdx.x & 63;   // node
    int qq   = threadIdx.x >> 6;   // qlocal = qq*8 .. +7
    for (int t = threadIdx.x; t < 4096; t += 256) {
        int c = t >> 3, k = t & 7;
        ((float4*)QpL)[t] = ((const float4*)(QpT + (size_t)c * 256 + qg * 32))[k];
    }
    __syncthreads();
    float acc[8] = {0, 0, 0, 0, 0, 0, 0, 0};
    const float* sbase = support + (size_t)w * 32768 + lane;
#pragma unroll 1
    for (int c0 = 0; c0 < 512; c0 += 8) {
        float x[8];
#pragma unroll
        for (int j = 0; j < 8; ++j) x[j] = sbase[(size_t)(c0 + j) * 64];
#pragma unroll
        for (int j = 0; j < 8; ++j) {
            float4 b0 = *(const float4*)(QpL + (c0 + j) * 32 + qq * 8);
            float4 b1 = *(const float4*)(QpL + (c0 + j) * 32 + qq * 8 + 4);
            acc[0] = fmaf(x[j], b0.x, acc[0]); acc[1] = fmaf(x[j], b0.y, acc[1]);
            acc[2] = fmaf(x[j], b0.z, acc[2]); acc[3] = fmaf(x[j], b0.w, acc[3]);
            acc[4] = fmaf(x[j], b1.x, acc[4]); acc[5] = fmaf(x[j], b1.y, acc[5]);
            acc[6] = fmaf(x[j], b1.z, acc[6]); acc[7] = fmaf(x[j], b1.w, acc[7]);
        }
    }
#pragma unroll
    for (int k = 0; k < 8; ++k) {
        float v = fmaxf(acc[k], 0.0f) + 0.001f;
        v += 1e-5f;
        float s = v;
        s += __shfl_xor(s, 1);  s += __shfl_xor(s, 2);  s += __shfl_xor(s, 4);
        s += __shfl_xor(s, 8);  s += __shfl_xor(s, 16); s += __shfl_xor(s, 32);
        int q = qg * 32 + qq * 8 + k;
        b_out[((size_t)w * 256 + q) * 64 + lane] = v * (64.0f / s);
    }
}

// --------- K3: MFMA sim -> rescaled fp16 Gibbs tiles in global --------------
// Wave per (q,w). Output layout Mg[p_loc][t][lane*8..+8] halves (coalesced).
__global__ void __launch_bounds__(256, 4)
sim_kernel(const _Float16* __restrict__ Uht, const _Float16* __restrict__ Vht,
           _Float16* __restrict__ Mg, float* __restrict__ s0A, int q0) {
    __shared__ __align__(16) float T[2][64 * LDP];   // 34.8 KB

    int bid  = blockIdx.x;
    int w    = bid & 31;
    int qg   = bid >> 5;
    int wave = threadIdx.x >> 6;
    int lane = threadIdx.x & 63;
    int q    = q0 + qg * 4 + wave;
    int lo16 = lane & 15;
    int hi4  = lane >> 4;
    int ig   = lane >> 3;
    int jg   = lane & 7;

    floatx4 acc[4][4];
#pragma unroll
    for (int tm = 0; tm < 4; ++tm)
#pragma unroll
        for (int tn = 0; tn < 4; ++tn)
            acc[tm][tn] = (floatx4){0.f, 0.f, 0.f, 0.f};

    const _Float16* Abase = Uht + (size_t)q * 32768;
    const _Float16* Bbase = Vht + (size_t)w * 32768;
#pragma unroll 1
    for (int kk = 0; kk < 16; ++kk) {
        int kc = kk * 32 + hi4 * 8;
        half8 bf[4];
#pragma unroll
        for (int t = 0; t < 4; ++t)
            bf[t] = *(const half8*)(Bbase + (size_t)(t * 16 + lo16) * 512 + kc);
#pragma unroll
        for (int tm = 0; tm < 4; ++tm) {
            half8 af = *(const half8*)(Abase + (size_t)(tm * 16 + lo16) * 512 + kc);
#pragma unroll
            for (int tn = 0; tn < 4; ++tn)
                acc[tm][tn] = __builtin_amdgcn_mfma_f32_16x16x32_f16(
                    af, bf[tn], acc[tm][tn], 0, 0, 0);
        }
    }

    // wave-uniform tile max for the fp16 rescale
    float lmax = -2.0f;
#pragma unroll
    for (int tm = 0; tm < 4; ++tm)
#pragma unroll
        for (int tn = 0; tn < 4; ++tn)
#pragma unroll
            for (int r = 0; r < 4; ++r) lmax = fmaxf(lmax, acc[tm][tn][r]);
    lmax = fmaxf(lmax, __shfl_xor(lmax, 1));
    lmax = fmaxf(lmax, __shfl_xor(lmax, 2));
    lmax = fmaxf(lmax, __shfl_xor(lmax, 4));
    lmax = fmaxf(lmax, __shfl_xor(lmax, 8));
    lmax = fmaxf(lmax, __shfl_xor(lmax, 16));
    lmax = fmaxf(lmax, __shfl_xor(lmax, 32));
    float s0 = lmax;

    // exp + LDS roundtrip into the xor-permuted (ig,jg) layout, fp16 on read
    half8 Mh[8];
#pragma unroll 1
    for (int round = 0; round < 2; ++round) {
        if ((wave >> 1) == round) {
            float* buf = T[wave & 1];
#pragma unroll
            for (int tm = 0; tm < 4; ++tm)
#pragma unroll
                for (int tn = 0; tn < 4; ++tn)
#pragma unroll
                    for (int r = 0; r < 4; ++r) {
                        int row = tm * 16 + hi4 * 4 + r;
                        int col = tn * 16 + lo16;
                        int sp  = (col & 7) ^ (row >> 3);
                        buf[row * LDP + (col & ~7) + sp] =
                            fexp2((acc[tm][tn][r] - s0) * K_SIM2M);
                    }
        }
        __syncthreads();
        if ((wave >> 1) == round) {
            const float* buf = T[wave & 1];
#pragma unroll
            for (int t = 0; t < 8; ++t) {
                const float* p = buf + (ig * 8 + (jg ^ t)) * LDP + jg * 8;
                float4 m0 = *(const float4*)p;
                float4 m1 = *(const float4*)(p + 4);
                half8 h;
                h[0] = (_Float16)m0.x; h[1] = (_Float16)m0.y;
                h[2] = (_Float16)m0.z; h[3] = (_Float16)m0.w;
                h[4] = (_Float16)m1.x; h[5] = (_Float16)m1.y;
                h[6] = (_Float16)m1.z; h[7] = (_Float16)m1.w;
                Mh[t] = h;
            }
        }
        __syncthreads();
    }

    int p_loc = (q - q0) * 32 + w;
    _Float16* mp = Mg + (size_t)p_loc * 4096 + lane * 8;
#pragma unroll
    for (int t = 0; t < 8; ++t) *(half8*)(mp + (size_t)t * 512) = Mh[t];
    if (lane == 0) s0A[q * 32 + w] = s0;
}

// --------- K4: Sinkhorn + logits. One wave per pair, no LDS, 8 waves/EU -----
__global__ void __launch_bounds__(64, 8)
skh_kernel(const _Float16* __restrict__ Mg, const float* __restrict__ s0A,
           const float* __restrict__ a_arr, const float* __restrict__ b_arr,
           float* __restrict__ out, int q0) {
    int p_loc = blockIdx.x;
    int lane  = threadIdx.x;
    int q  = q0 + (p_loc >> 5);
    int w  = p_loc & 31;
    int gp = q * 32 + w;
    int ig = lane >> 3;
    int jg = lane & 7;

    const _Float16* mp = Mg + (size_t)p_loc * 4096 + lane * 8;
    half8 Mh[8];
#pragma unroll
    for (int t = 0; t < 8; ++t) Mh[t] = *(const half8*)(mp + (size_t)t * 512);

    float a_own = a_arr[(size_t)gp * 64 + ig * 8 + jg];
    float b_own = b_arr[((size_t)w * 256 + q) * 64 + jg * 8 + ig];

    float wvp[8];
#pragma unroll
    for (int s = 0; s < 8; ++s) wvp[s] = 1.0f;
    float q8[8];
    float w_prev = -1.f;

#pragma unroll 1
    for (int it = 0; it < 100; ++it) {
        float p[8];
#pragma unroll
        for (int t = 0; t < 8; ++t) {
            float s = (float)Mh[t][0] * wvp[0];
#pragma unroll
            for (int c = 1; c < 8; ++c) s = fmaf((float)Mh[t][c], wvp[c], s);
            p[t] = s;
        }
        p[0] += __shfl_xor(p[4], 4); p[1] += __shfl_xor(p[5], 4);
        p[2] += __shfl_xor(p[6], 4); p[3] += __shfl_xor(p[7], 4);
        p[0] += __shfl_xor(p[2], 2); p[1] += __shfl_xor(p[3], 2);
        p[0] += __shfl_xor(p[1], 1);
        float z_own = a_own * fast_rcp(p[0]);
        q8[0] = z_own;
        q8[1] = __shfl_xor(q8[0], 1);
        q8[2] = __shfl_xor(q8[0], 2); q8[3] = __shfl_xor(q8[1], 2);
        q8[4] = __shfl_xor(q8[0], 4); q8[5] = __shfl_xor(q8[1], 4);
        q8[6] = __shfl_xor(q8[2], 4); q8[7] = __shfl_xor(q8[3], 4);
        float cp[8];
#pragma unroll
        for (int s = 0; s < 8; ++s) {
            float v = (float)Mh[0][s] * q8[0];
#pragma unroll
            for (int t = 1; t < 8; ++t) v = fmaf((float)Mh[t][s], q8[t], v);
            cp[s] = v;
        }
        cp[0] += __shfl_xor(cp[4], 32); cp[1] += __shfl_xor(cp[5], 32);
        cp[2] += __shfl_xor(cp[6], 32); cp[3] += __shfl_xor(cp[7], 32);
        cp[0] += __shfl_xor(cp[2], 16); cp[1] += __shfl_xor(cp[3], 16);
        cp[0] += __shfl_xor(cp[1], 8);
        float w_own = b_own * fast_rcp(cp[0]);
        wvp[0] = w_own;
        wvp[1] = __shfl_xor(wvp[0], 8);
        wvp[2] = __shfl_xor(wvp[0], 16); wvp[3] = __shfl_xor(wvp[1], 16);
        wvp[4] = __shfl_xor(wvp[0], 32); wvp[5] = __shfl_xor(wvp[1], 32);
        wvp[6] = __shfl_xor(wvp[2], 32); wvp[7] = __shfl_xor(wvp[3], 32);
        // w stable across all 64 cols -> next z,w identical -> fixed point
        bool same = fabsf(w_own - w_prev) <= 1e-5f * w_own;
        w_prev = w_own;
        if (__all(same)) break;
    }

    float s0 = s0A[gp];
    float s = 0.f;
#pragma unroll
    for (int t = 0; t < 8; ++t)
#pragma unroll
        for (int c = 0; c < 8; ++c) {
            float m    = fmaxf((float)Mh[t][c], 1e-30f);
            float sim  = fmaf(flog2(m), K_M2SIM, s0);
            float flow = q8[t] * m * wvp[c];
            s = fmaf(sim, flow, s);
        }
    s += __shfl_xor(s, 1);  s += __shfl_xor(s, 2);  s += __shfl_xor(s, 4);
    s += __shfl_xor(s, 8);  s += __shfl_xor(s, 16); s += __shfl_xor(s, 32);
    if (lane == 0) out[gp] = s * 0.1953125f;   // 12.5/64
}

// ---------------------------------------------------------------------------
extern "C" void kernel_launch(void* const* d_in, const int* in_sizes, int n_in,
                              void* d_out, int out_size, void* d_ws, size_t ws_size,
                              hipStream_t stream) {
    (void)in_sizes; (void)n_in; (void)out_size;
    const float* support = (const float*)d_in[0];   // 32*512*64
    const float* query   = (const float*)d_in[1];   // 256*512*64

    char* ws = (char*)d_ws;
    _Float16* Uht = (_Float16*)ws;                  // 16 MB
    _Float16* Vht = Uht + 8388608;                  //  2 MB
    float* BpT = (float*)(Vht + 1048576);           // 64 KB  [512][32]
    float* QpT = BpT + 16384;                       // 512 KB [512][256]
    float* aA  = QpT + 131072;                      //  2 MB
    float* bA  = aA + 524288;                       //  2 MB
    float* s0A = bA + 524288;                       // 32 KB
    _Float16* Mg = (_Float16*)(s0A + 8192);         // up to 64 MB
    size_t base = (size_t)((char*)Mg - ws);

    int nsplit = 1;                                 // adaptive to ws_size
    if (ws_size < base + (size_t)64 * 1024 * 1024) nsplit = 2;
    if (ws_size < base + (size_t)32 * 1024 * 1024) nsplit = 4;

    norm_kernel <<<288, 256, 0, stream>>>(support, query, Vht, Uht, BpT, QpT);
    amarg_kernel<<<256, 256, 0, stream>>>(query, BpT, aA);
    bmarg_kernel<<<256, 256, 0, stream>>>(support, QpT, bA);
    int qchunk = 256 / nsplit;
    for (int s = 0; s < nsplit; ++s) {
        sim_kernel<<<2048 / nsplit, 256, 0, stream>>>(Uht, Vht, Mg, s0A, s * qchunk);
        skh_kernel<<<8192 / nsplit,  64, 0, stream>>>(Mg, s0A, aA, bA,
                                                      (float*)d_out, s * qchunk);
    }
}

// Round 6
// 427.500 us; speedup vs baseline: 1.2230x; 1.2230x over previous
//
#include <hip/hip_runtime.h>
#include <math.h>

// ---------------------------------------------------------------------------
// EMD layer (Sinkhorn-OT logits) for MI355X.
// support: [32,512,8,8] f32, query: [256,512,8,8] f32 -> logits [256,32] f32.
//
// R6: fix R5's skh spill: 4 pair-waves per 256-block, launch_bounds(256,6)
//     (85-VGPR budget; loop live set ~60 -> no spill, 24 waves/CU).
//     amarg+bmarg merged into one 512-block dispatch for 2x prep occupancy.
//     sim_kernel / norm_kernel unchanged from R5.
// ---------------------------------------------------------------------------

#define DEV static __device__ __forceinline__

typedef _Float16 half8 __attribute__((ext_vector_type(8)));
typedef float floatx4 __attribute__((ext_vector_type(4)));

DEV float fast_rcp(float x) {
#if __has_builtin(__builtin_amdgcn_rcpf)
    return __builtin_amdgcn_rcpf(x);
#else
    return 1.0f / x;
#endif
}
DEV float fexp2(float x) {
#if __has_builtin(__builtin_amdgcn_exp2f)
    return __builtin_amdgcn_exp2f(x);
#else
    return exp2f(x);
#endif
}
DEV float flog2(float x) {
#if __has_builtin(__builtin_amdgcn_logf)
    return __builtin_amdgcn_logf(x);
#else
    return log2f(x);
#endif
}

#define K_SIM2M 28.853900817779268f    // 20/ln2 : M = 2^((sim-1)*K_SIM2M)
#define K_M2SIM 0.034657359027997264f  // 0.05*ln2 : sim = 1 + log2(M)*K_M2SIM
#define LDP 68                         // padded LDS row stride (floats)

// ------ K1: center+normalize over C -> fp16 node-major, + pooled means ------
__global__ void __launch_bounds__(256)
norm_kernel(const float* __restrict__ support, const float* __restrict__ query,
            _Float16* __restrict__ Vht, _Float16* __restrict__ Uht,
            float* __restrict__ BpT, float* __restrict__ QpT) {
    __shared__ float red1[4][64];
    __shared__ float red2[4][64];
    __shared__ float muL[64], invL[64];
    __shared__ float tile[128][65];

    int sid = blockIdx.x;             // 0..287
    const float* src;
    _Float16* dst;
    float* poolT;
    int pstride, pidx;
    if (sid < 32) {
        src = support + (size_t)sid * 32768; dst = Vht + (size_t)sid * 32768;
        poolT = BpT; pstride = 32; pidx = sid;
    } else {
        src = query + (size_t)(sid - 32) * 32768; dst = Uht + (size_t)(sid - 32) * 32768;
        poolT = QpT; pstride = 256; pidx = sid - 32;
    }

    int node = threadIdx.x & 63;
    int cq   = threadIdx.x >> 6;      // wave index = c-quarter

    float s1 = 0.f, s2 = 0.f;
#pragma unroll 8
    for (int j = 0; j < 128; ++j) {
        int c = cq * 128 + j;
        float x = src[c * 64 + node];
        s1 += x; s2 += x * x;
        float ps = x;                  // pool: sum over the wave's 64 nodes
        ps += __shfl_xor(ps, 1);  ps += __shfl_xor(ps, 2);  ps += __shfl_xor(ps, 4);
        ps += __shfl_xor(ps, 8);  ps += __shfl_xor(ps, 16); ps += __shfl_xor(ps, 32);
        if (node == 0) poolT[(size_t)c * pstride + pidx] = ps * (1.0f / 64.0f);
    }
    red1[cq][node] = s1;
    red2[cq][node] = s2;
    __syncthreads();
    if (threadIdx.x < 64) {
        float t1 = red1[0][node] + red1[1][node] + red1[2][node] + red1[3][node];
        float t2 = red2[0][node] + red2[1][node] + red2[2][node] + red2[3][node];
        float mu = t1 * (1.0f / 512.0f);
        float ss = t2 - 512.0f * mu * mu;
        muL[node]  = mu;
        invL[node] = 1.0f / fmaxf(sqrtf(fmaxf(ss, 0.0f)), 1e-8f);
    }
    __syncthreads();

    for (int ch = 0; ch < 4; ++ch) {
        float mu = muL[node], inv = invL[node];
#pragma unroll 4
        for (int j = 0; j < 32; ++j) {
            int cl = cq * 32 + j;
            float x = src[(ch * 128 + cl) * 64 + node];
            tile[cl][node] = (x - mu) * inv;
        }
        __syncthreads();
#pragma unroll
        for (int r = 0; r < 4; ++r) {
            int lin = r * 256 + threadIdx.x;
            int nd  = lin >> 4;
            int c8  = lin & 15;
            half8 v;
#pragma unroll
            for (int i = 0; i < 8; ++i) v[i] = (_Float16)tile[c8 * 8 + i][nd];
            *(half8*)(dst + (size_t)nd * 512 + ch * 128 + c8 * 8) = v;
        }
        __syncthreads();
    }
}

// --------- K2: merged a/b marginals (512 blocks -> 2 blocks/CU) -------------
__global__ void __launch_bounds__(256)
marg_kernel(const float* __restrict__ query, const float* __restrict__ support,
            const float* __restrict__ BpT, const float* __restrict__ QpT,
            float* __restrict__ a_out, float* __restrict__ b_out) {
    __shared__ __align__(16) float WL[512 * 32];   // [c][k] 64 KB
    int lane = threadIdx.x & 63;   // node
    int kq   = threadIdx.x >> 6;   // k = kq*8 .. +7

    const float* sbase;
    if (blockIdx.x < 256) {
        // a-marginals: block per q, k enumerates w (32)
        int q = blockIdx.x;
        for (int t = threadIdx.x; t < 4096; t += 256)
            ((float4*)WL)[t] = ((const float4*)BpT)[t];
        sbase = query + (size_t)q * 32768 + lane;
    } else {
        // b-marginals: block per (w, q-group of 32), k enumerates qlocal
        int id = blockIdx.x - 256;
        int w = id >> 3, qg = id & 7;
        for (int t = threadIdx.x; t < 4096; t += 256) {
            int c = t >> 3, k = t & 7;
            ((float4*)WL)[t] = ((const float4*)(QpT + (size_t)c * 256 + qg * 32))[k];
        }
        sbase = support + (size_t)w * 32768 + lane;
    }
    __syncthreads();

    float acc[8] = {0, 0, 0, 0, 0, 0, 0, 0};
#pragma unroll 1
    for (int c0 = 0; c0 < 512; c0 += 8) {
        float x[8];
#pragma unroll
        for (int j = 0; j < 8; ++j) x[j] = sbase[(size_t)(c0 + j) * 64];
#pragma unroll
        for (int j = 0; j < 8; ++j) {
            float4 b0 = *(const float4*)(WL + (c0 + j) * 32 + kq * 8);
            float4 b1 = *(const float4*)(WL + (c0 + j) * 32 + kq * 8 + 4);
            acc[0] = fmaf(x[j], b0.x, acc[0]); acc[1] = fmaf(x[j], b0.y, acc[1]);
            acc[2] = fmaf(x[j], b0.z, acc[2]); acc[3] = fmaf(x[j], b0.w, acc[3]);
            acc[4] = fmaf(x[j], b1.x, acc[4]); acc[5] = fmaf(x[j], b1.y, acc[5]);
            acc[6] = fmaf(x[j], b1.z, acc[6]); acc[7] = fmaf(x[j], b1.w, acc[7]);
        }
    }
#pragma unroll
    for (int k = 0; k < 8; ++k) {
        float v = fmaxf(acc[k], 0.0f) + 0.001f;
        v += 1e-5f;
        float s = v;
        s += __shfl_xor(s, 1);  s += __shfl_xor(s, 2);  s += __shfl_xor(s, 4);
        s += __shfl_xor(s, 8);  s += __shfl_xor(s, 16); s += __shfl_xor(s, 32);
        v = v * (64.0f / s);
        if (blockIdx.x < 256) {
            int q = blockIdx.x, w = kq * 8 + k;
            a_out[((size_t)q * 32 + w) * 64 + lane] = v;
        } else {
            int id = blockIdx.x - 256;
            int w = id >> 3, q = (id & 7) * 32 + kq * 8 + k;
            b_out[((size_t)w * 256 + q) * 64 + lane] = v;
        }
    }
}

// --------- K3: MFMA sim -> rescaled fp16 Gibbs tiles in global --------------
__global__ void __launch_bounds__(256, 4)
sim_kernel(const _Float16* __restrict__ Uht, const _Float16* __restrict__ Vht,
           _Float16* __restrict__ Mg, float* __restrict__ s0A, int q0) {
    __shared__ __align__(16) float T[2][64 * LDP];   // 34.8 KB

    int bid  = blockIdx.x;
    int w    = bid & 31;
    int qg   = bid >> 5;
    int wave = threadIdx.x >> 6;
    int lane = threadIdx.x & 63;
    int q    = q0 + qg * 4 + wave;
    int lo16 = lane & 15;
    int hi4  = lane >> 4;
    int ig   = lane >> 3;
    int jg   = lane & 7;

    floatx4 acc[4][4];
#pragma unroll
    for (int tm = 0; tm < 4; ++tm)
#pragma unroll
        for (int tn = 0; tn < 4; ++tn)
            acc[tm][tn] = (floatx4){0.f, 0.f, 0.f, 0.f};

    const _Float16* Abase = Uht + (size_t)q * 32768;
    const _Float16* Bbase = Vht + (size_t)w * 32768;
#pragma unroll 1
    for (int kk = 0; kk < 16; ++kk) {
        int kc = kk * 32 + hi4 * 8;
        half8 bf[4];
#pragma unroll
        for (int t = 0; t < 4; ++t)
            bf[t] = *(const half8*)(Bbase + (size_t)(t * 16 + lo16) * 512 + kc);
#pragma unroll
        for (int tm = 0; tm < 4; ++tm) {
            half8 af = *(const half8*)(Abase + (size_t)(tm * 16 + lo16) * 512 + kc);
#pragma unroll
            for (int tn = 0; tn < 4; ++tn)
                acc[tm][tn] = __builtin_amdgcn_mfma_f32_16x16x32_f16(
                    af, bf[tn], acc[tm][tn], 0, 0, 0);
        }
    }

    // wave-uniform tile max for the fp16 rescale
    float lmax = -2.0f;
#pragma unroll
    for (int tm = 0; tm < 4; ++tm)
#pragma unroll
        for (int tn = 0; tn < 4; ++tn)
#pragma unroll
            for (int r = 0; r < 4; ++r) lmax = fmaxf(lmax, acc[tm][tn][r]);
    lmax = fmaxf(lmax, __shfl_xor(lmax, 1));
    lmax = fmaxf(lmax, __shfl_xor(lmax, 2));
    lmax = fmaxf(lmax, __shfl_xor(lmax, 4));
    lmax = fmaxf(lmax, __shfl_xor(lmax, 8));
    lmax = fmaxf(lmax, __shfl_xor(lmax, 16));
    lmax = fmaxf(lmax, __shfl_xor(lmax, 32));
    float s0 = lmax;

    // exp + LDS roundtrip into the xor-permuted (ig,jg) layout, fp16 on read
    half8 Mh[8];
#pragma unroll 1
    for (int round = 0; round < 2; ++round) {
        if ((wave >> 1) == round) {
            float* buf = T[wave & 1];
#pragma unroll
            for (int tm = 0; tm < 4; ++tm)
#pragma unroll
                for (int tn = 0; tn < 4; ++tn)
#pragma unroll
                    for (int r = 0; r < 4; ++r) {
                        int row = tm * 16 + hi4 * 4 + r;
                        int col = tn * 16 + lo16;
                        int sp  = (col & 7) ^ (row >> 3);
                        buf[row * LDP + (col & ~7) + sp] =
                            fexp2((acc[tm][tn][r] - s0) * K_SIM2M);
                    }
        }
        __syncthreads();
        if ((wave >> 1) == round) {
            const float* buf = T[wave & 1];
#pragma unroll
            for (int t = 0; t < 8; ++t) {
                const float* p = buf + (ig * 8 + (jg ^ t)) * LDP + jg * 8;
                float4 m0 = *(const float4*)p;
                float4 m1 = *(const float4*)(p + 4);
                half8 h;
                h[0] = (_Float16)m0.x; h[1] = (_Float16)m0.y;
                h[2] = (_Float16)m0.z; h[3] = (_Float16)m0.w;
                h[4] = (_Float16)m1.x; h[5] = (_Float16)m1.y;
                h[6] = (_Float16)m1.z; h[7] = (_Float16)m1.w;
                Mh[t] = h;
            }
        }
        __syncthreads();
    }

    int p_loc = (q - q0) * 32 + w;
    _Float16* mp = Mg + (size_t)p_loc * 4096 + lane * 8;
#pragma unroll
    for (int t = 0; t < 8; ++t) *(half8*)(mp + (size_t)t * 512) = Mh[t];
    if (lane == 0) s0A[q * 32 + w] = s0;
}

// --------- K4: Sinkhorn + logits. 4 pair-waves per block, 6 waves/EU --------
// launch_bounds(256,6): 85-VGPR budget, loop live set ~60 -> no spill.
__global__ void __launch_bounds__(256, 6)
skh_kernel(const _Float16* __restrict__ Mg, const float* __restrict__ s0A,
           const float* __restrict__ a_arr, const float* __restrict__ b_arr,
           float* __restrict__ out, int q0) {
    int wave  = threadIdx.x >> 6;
    int lane  = threadIdx.x & 63;
    int p_loc = blockIdx.x * 4 + wave;
    int q  = q0 + (p_loc >> 5);
    int w  = p_loc & 31;
    int gp = q * 32 + w;
    int ig = lane >> 3;
    int jg = lane & 7;

    const _Float16* mp = Mg + (size_t)p_loc * 4096 + lane * 8;
    half8 Mh[8];
#pragma unroll
    for (int t = 0; t < 8; ++t) Mh[t] = *(const half8*)(mp + (size_t)t * 512);

    float a_own = a_arr[(size_t)gp * 64 + ig * 8 + jg];
    float b_own = b_arr[((size_t)w * 256 + q) * 64 + jg * 8 + ig];

    float wvp[8];
#pragma unroll
    for (int s = 0; s < 8; ++s) wvp[s] = 1.0f;
    float q8[8];
    float w_prev = -1.f;

#pragma unroll 1
    for (int it = 0; it < 100; ++it) {
        float p[8];
#pragma unroll
        for (int t = 0; t < 8; ++t) {
            float s = (float)Mh[t][0] * wvp[0];
#pragma unroll
            for (int c = 1; c < 8; ++c) s = fmaf((float)Mh[t][c], wvp[c], s);
            p[t] = s;
        }
        p[0] += __shfl_xor(p[4], 4); p[1] += __shfl_xor(p[5], 4);
        p[2] += __shfl_xor(p[6], 4); p[3] += __shfl_xor(p[7], 4);
        p[0] += __shfl_xor(p[2], 2); p[1] += __shfl_xor(p[3], 2);
        p[0] += __shfl_xor(p[1], 1);
        float z_own = a_own * fast_rcp(p[0]);
        q8[0] = z_own;
        q8[1] = __shfl_xor(q8[0], 1);
        q8[2] = __shfl_xor(q8[0], 2); q8[3] = __shfl_xor(q8[1], 2);
        q8[4] = __shfl_xor(q8[0], 4); q8[5] = __shfl_xor(q8[1], 4);
        q8[6] = __shfl_xor(q8[2], 4); q8[7] = __shfl_xor(q8[3], 4);
        float cp[8];
#pragma unroll
        for (int s = 0; s < 8; ++s) {
            float v = (float)Mh[0][s] * q8[0];
#pragma unroll
            for (int t = 1; t < 8; ++t) v = fmaf((float)Mh[t][s], q8[t], v);
            cp[s] = v;
        }
        cp[0] += __shfl_xor(cp[4], 32); cp[1] += __shfl_xor(cp[5], 32);
        cp[2] += __shfl_xor(cp[6], 32); cp[3] += __shfl_xor(cp[7], 32);
        cp[0] += __shfl_xor(cp[2], 16); cp[1] += __shfl_xor(cp[3], 16);
        cp[0] += __shfl_xor(cp[1], 8);
        float w_own = b_own * fast_rcp(cp[0]);
        wvp[0] = w_own;
        wvp[1] = __shfl_xor(wvp[0], 8);
        wvp[2] = __shfl_xor(wvp[0], 16); wvp[3] = __shfl_xor(wvp[1], 16);
        wvp[4] = __shfl_xor(wvp[0], 32); wvp[5] = __shfl_xor(wvp[1], 32);
        wvp[6] = __shfl_xor(wvp[2], 32); wvp[7] = __shfl_xor(wvp[3], 32);
        // w stable across all 64 cols -> next z,w identical -> fixed point
        bool same = fabsf(w_own - w_prev) <= 1e-5f * w_own;
        w_prev = w_own;
        if (__all(same)) break;
    }

    float s0 = s0A[gp];
    float s = 0.f;
#pragma unroll
    for (int t = 0; t < 8; ++t)
#pragma unroll
        for (int c = 0; c < 8; ++c) {
            float m    = fmaxf((float)Mh[t][c], 1e-30f);
            float sim  = fmaf(flog2(m), K_M2SIM, s0);
            float flow = q8[t] * m * wvp[c];
            s = fmaf(sim, flow, s);
        }
    s += __shfl_xor(s, 1);  s += __shfl_xor(s, 2);  s += __shfl_xor(s, 4);
    s += __shfl_xor(s, 8);  s += __shfl_xor(s, 16); s += __shfl_xor(s, 32);
    if (lane == 0) out[gp] = s * 0.1953125f;   // 12.5/64
}

// ---------------------------------------------------------------------------
extern "C" void kernel_launch(void* const* d_in, const int* in_sizes, int n_in,
                              void* d_out, int out_size, void* d_ws, size_t ws_size,
                              hipStream_t stream) {
    (void)in_sizes; (void)n_in; (void)out_size;
    const float* support = (const float*)d_in[0];   // 32*512*64
    const float* query   = (const float*)d_in[1];   // 256*512*64

    char* ws = (char*)d_ws;
    _Float16* Uht = (_Float16*)ws;                  // 16 MB
    _Float16* Vht = Uht + 8388608;                  //  2 MB
    float* BpT = (float*)(Vht + 1048576);           // 64 KB  [512][32]
    float* QpT = BpT + 16384;                       // 512 KB [512][256]
    float* aA  = QpT + 131072;                      //  2 MB
    float* bA  = aA + 524288;                       //  2 MB
    float* s0A = bA + 524288;                       // 32 KB
    _Float16* Mg = (_Float16*)(s0A + 8192);         // up to 64 MB
    size_t base = (size_t)((char*)Mg - ws);

    int nsplit = 1;                                 // adaptive to ws_size
    if (ws_size < base + (size_t)64 * 1024 * 1024) nsplit = 2;
    if (ws_size < base + (size_t)32 * 1024 * 1024) nsplit = 4;

    norm_kernel<<<288, 256, 0, stream>>>(support, query, Vht, Uht, BpT, QpT);
    marg_kernel<<<512, 256, 0, stream>>>(query, support, BpT, QpT, aA, bA);
    int qchunk = 256 / nsplit;
    for (int s = 0; s < nsplit; ++s) {
        sim_kernel<<<2048 / nsplit, 256, 0, stream>>>(Uht, Vht, Mg, s0A, s * qchunk);
        skh_kernel<<<2048 / nsplit, 256, 0, stream>>>(Mg, s0A, aA, bA,
                                                      (float*)d_out, s * qchunk);
    }
}

// Round 7
// 416.695 us; speedup vs baseline: 1.2547x; 1.0259x over previous
//
#include <hip/hip_runtime.h>
#include <math.h>

// ---------------------------------------------------------------------------
// EMD layer (Sinkhorn-OT logits) for MI355X.
// support: [32,512,8,8] f32, query: [256,512,8,8] f32 -> logits [256,32] f32.
//
// R7: (1) XCD-residency swizzle in sim: blockIdx%8 picks the q-group so each
//     XCD's L2 holds 32 Uht rows (2MB) + Vht (2MB) -> k-loop loads hit L2.
//     (2) marg computes raw dots from fp16 Uht/Vht via
//     dot_raw = nrm*dot_fp16 + mu*S  (norm emits mu/nrm/S), dropping the
//     151 MB raw re-read. marg uses the same q<->XCD grouping to pre-warm L2.
// ---------------------------------------------------------------------------

#define DEV static __device__ __forceinline__

typedef _Float16 half8 __attribute__((ext_vector_type(8)));
typedef float floatx4 __attribute__((ext_vector_type(4)));

DEV float fast_rcp(float x) {
#if __has_builtin(__builtin_amdgcn_rcpf)
    return __builtin_amdgcn_rcpf(x);
#else
    return 1.0f / x;
#endif
}
DEV float fexp2(float x) {
#if __has_builtin(__builtin_amdgcn_exp2f)
    return __builtin_amdgcn_exp2f(x);
#else
    return exp2f(x);
#endif
}
DEV float flog2(float x) {
#if __has_builtin(__builtin_amdgcn_logf)
    return __builtin_amdgcn_logf(x);
#else
    return log2f(x);
#endif
}

#define K_SIM2M 28.853900817779268f    // 20/ln2 : M = 2^((sim-1)*K_SIM2M)
#define K_M2SIM 0.034657359027997264f  // 0.05*ln2 : sim = 1 + log2(M)*K_M2SIM
#define LDP 68                         // padded LDS row stride (floats)

// ------ K1: center+normalize over C -> fp16 node-major, + pool/mu/nrm/S -----
__global__ void __launch_bounds__(256)
norm_kernel(const float* __restrict__ support, const float* __restrict__ query,
            _Float16* __restrict__ Vht, _Float16* __restrict__ Uht,
            float* __restrict__ BpT, float* __restrict__ QpT,
            float* __restrict__ muA, float* __restrict__ nrmA,
            float* __restrict__ Ssc) {
    __shared__ float red1[4][64];
    __shared__ float red2[4][64];
    __shared__ float muL[64], invL[64];
    __shared__ float tile[128][65];

    int sid = blockIdx.x;             // 0..287
    const float* src;
    _Float16* dst;
    float* poolT;
    int pstride, pidx;
    if (sid < 32) {
        src = support + (size_t)sid * 32768; dst = Vht + (size_t)sid * 32768;
        poolT = BpT; pstride = 32; pidx = sid;
    } else {
        src = query + (size_t)(sid - 32) * 32768; dst = Uht + (size_t)(sid - 32) * 32768;
        poolT = QpT; pstride = 256; pidx = sid - 32;
    }

    int node = threadIdx.x & 63;
    int cq   = threadIdx.x >> 6;      // wave index = c-quarter

    float s1 = 0.f, s2 = 0.f;
#pragma unroll 8
    for (int j = 0; j < 128; ++j) {
        int c = cq * 128 + j;
        float x = src[c * 64 + node];
        s1 += x; s2 += x * x;
        float ps = x;                  // pool: sum over the wave's 64 nodes
        ps += __shfl_xor(ps, 1);  ps += __shfl_xor(ps, 2);  ps += __shfl_xor(ps, 4);
        ps += __shfl_xor(ps, 8);  ps += __shfl_xor(ps, 16); ps += __shfl_xor(ps, 32);
        if (node == 0) poolT[(size_t)c * pstride + pidx] = ps * (1.0f / 64.0f);
    }
    red1[cq][node] = s1;
    red2[cq][node] = s2;
    __syncthreads();
    if (threadIdx.x < 64) {
        float t1 = red1[0][node] + red1[1][node] + red1[2][node] + red1[3][node];
        float t2 = red2[0][node] + red2[1][node] + red2[2][node] + red2[3][node];
        float mu  = t1 * (1.0f / 512.0f);
        float ss  = t2 - 512.0f * mu * mu;
        float nrm = fmaxf(sqrtf(fmaxf(ss, 0.0f)), 1e-8f);
        muL[node]  = mu;
        invL[node] = 1.0f / nrm;
        muA[sid * 64 + node]  = mu;
        nrmA[sid * 64 + node] = nrm;
        // S = sum_c pool[c] = (1/64) * sum_nodes t1
        float sS = t1;
        sS += __shfl_xor(sS, 1);  sS += __shfl_xor(sS, 2);  sS += __shfl_xor(sS, 4);
        sS += __shfl_xor(sS, 8);  sS += __shfl_xor(sS, 16); sS += __shfl_xor(sS, 32);
        if (node == 0) Ssc[sid] = sS * (1.0f / 64.0f);
    }
    __syncthreads();

    for (int ch = 0; ch < 4; ++ch) {
        float mu = muL[node], inv = invL[node];
#pragma unroll 4
        for (int j = 0; j < 32; ++j) {
            int cl = cq * 32 + j;
            float x = src[(ch * 128 + cl) * 64 + node];
            tile[cl][node] = (x - mu) * inv;
        }
        __syncthreads();
#pragma unroll
        for (int r = 0; r < 4; ++r) {
            int lin = r * 256 + threadIdx.x;
            int nd  = lin >> 4;
            int c8  = lin & 15;
            half8 v;
#pragma unroll
            for (int i = 0; i < 8; ++i) v[i] = (_Float16)tile[c8 * 8 + i][nd];
            *(half8*)(dst + (size_t)nd * 512 + ch * 128 + c8 * 8) = v;
        }
        __syncthreads();
    }
}

// --------- K2: merged a/b marginals from fp16 + (mu, nrm, S) ---------------
// raw_dot = nrm * <fp16 normalized vec, pooled vec> + mu * S(pooled vec)
__global__ void __launch_bounds__(256)
marg_kernel(const _Float16* __restrict__ Uht, const _Float16* __restrict__ Vht,
            const float* __restrict__ BpT, const float* __restrict__ QpT,
            const float* __restrict__ muA, const float* __restrict__ nrmA,
            const float* __restrict__ Ssc,
            float* __restrict__ a_out, float* __restrict__ b_out) {
    __shared__ __align__(16) float WL[512 * 32];   // [c][k] 64 KB
    __shared__ float Sl[32];
    int lane = threadIdx.x & 63;   // node
    int kq   = threadIdx.x >> 6;   // k = kq*8 .. +7

    const _Float16* src16;
    float mu, nrm;
    if (blockIdx.x < 256) {
        // a-marginals: block per q (XCD-grouped), k enumerates w (32)
        int q = (blockIdx.x & 7) * 32 + (blockIdx.x >> 3);
        for (int t = threadIdx.x; t < 4096; t += 256)
            ((float4*)WL)[t] = ((const float4*)BpT)[t];
        if (threadIdx.x < 32) Sl[threadIdx.x] = Ssc[threadIdx.x];  // S_w
        src16 = Uht + (size_t)q * 32768 + (size_t)lane * 512;
        mu  = muA[(32 + q) * 64 + lane];
        nrm = nrmA[(32 + q) * 64 + lane];
    } else {
        // b-marginals: block per (w, q-group of 32), k enumerates qlocal
        int id = blockIdx.x - 256;
        int w = id >> 3, qg = id & 7;
        for (int t = threadIdx.x; t < 4096; t += 256) {
            int c = t >> 3, k = t & 7;
            ((float4*)WL)[t] = ((const float4*)(QpT + (size_t)c * 256 + qg * 32))[k];
        }
        if (threadIdx.x < 32) Sl[threadIdx.x] = Ssc[32 + qg * 32 + threadIdx.x]; // S'_q
        src16 = Vht + (size_t)w * 32768 + (size_t)lane * 512;
        mu  = muA[w * 64 + lane];
        nrm = nrmA[w * 64 + lane];
    }
    __syncthreads();

    float acc[8] = {0, 0, 0, 0, 0, 0, 0, 0};
#pragma unroll 1
    for (int c0 = 0; c0 < 512; c0 += 8) {
        half8 x8 = *(const half8*)(src16 + c0);
#pragma unroll
        for (int j = 0; j < 8; ++j) {
            float xv = (float)x8[j];
            float4 b0 = *(const float4*)(WL + (c0 + j) * 32 + kq * 8);
            float4 b1 = *(const float4*)(WL + (c0 + j) * 32 + kq * 8 + 4);
            acc[0] = fmaf(xv, b0.x, acc[0]); acc[1] = fmaf(xv, b0.y, acc[1]);
            acc[2] = fmaf(xv, b0.z, acc[2]); acc[3] = fmaf(xv, b0.w, acc[3]);
            acc[4] = fmaf(xv, b1.x, acc[4]); acc[5] = fmaf(xv, b1.y, acc[5]);
            acc[6] = fmaf(xv, b1.z, acc[6]); acc[7] = fmaf(xv, b1.w, acc[7]);
        }
    }
#pragma unroll
    for (int k = 0; k < 8; ++k) {
        float raw = fmaf(mu, Sl[kq * 8 + k], nrm * acc[k]);
        float v = fmaxf(raw, 0.0f) + 0.001f;
        v += 1e-5f;
        float s = v;
        s += __shfl_xor(s, 1);  s += __shfl_xor(s, 2);  s += __shfl_xor(s, 4);
        s += __shfl_xor(s, 8);  s += __shfl_xor(s, 16); s += __shfl_xor(s, 32);
        v = v * (64.0f / s);
        if (blockIdx.x < 256) {
            int q = (blockIdx.x & 7) * 32 + (blockIdx.x >> 3), w = kq * 8 + k;
            a_out[((size_t)q * 32 + w) * 64 + lane] = v;
        } else {
            int id = blockIdx.x - 256;
            int w = id >> 3, q = (id & 7) * 32 + kq * 8 + k;
            b_out[((size_t)w * 256 + q) * 64 + lane] = v;
        }
    }
}

// --------- K3: MFMA sim -> rescaled fp16 Gibbs tiles, XCD-resident ----------
// blockIdx%8 = XCD x handles q in [x*qchunk/8 .. ), so Uht slice (<=2MB) +
// Vht (2MB) stay L2-resident per XCD.
__global__ void __launch_bounds__(256, 4)
sim_kernel(const _Float16* __restrict__ Uht, const _Float16* __restrict__ Vht,
           _Float16* __restrict__ Mg, float* __restrict__ s0A,
           int q0, int qchunk) {
    __shared__ __align__(16) float T[2][64 * LDP];   // 34.8 KB

    int x    = blockIdx.x & 7;
    int i    = blockIdx.x >> 3;
    int w    = i & 31;
    int wave = threadIdx.x >> 6;
    int lane = threadIdx.x & 63;
    int q    = q0 + (x * (qchunk >> 5) + (i >> 5)) * 4 + wave;
    int lo16 = lane & 15;
    int hi4  = lane >> 4;
    int ig   = lane >> 3;
    int jg   = lane & 7;

    floatx4 acc[4][4];
#pragma unroll
    for (int tm = 0; tm < 4; ++tm)
#pragma unroll
        for (int tn = 0; tn < 4; ++tn)
            acc[tm][tn] = (floatx4){0.f, 0.f, 0.f, 0.f};

    const _Float16* Abase = Uht + (size_t)q * 32768;
    const _Float16* Bbase = Vht + (size_t)w * 32768;
#pragma unroll 1
    for (int kk = 0; kk < 16; ++kk) {
        int kc = kk * 32 + hi4 * 8;
        half8 bf[4];
#pragma unroll
        for (int t = 0; t < 4; ++t)
            bf[t] = *(const half8*)(Bbase + (size_t)(t * 16 + lo16) * 512 + kc);
#pragma unroll
        for (int tm = 0; tm < 4; ++tm) {
            half8 af = *(const half8*)(Abase + (size_t)(tm * 16 + lo16) * 512 + kc);
#pragma unroll
            for (int tn = 0; tn < 4; ++tn)
                acc[tm][tn] = __builtin_amdgcn_mfma_f32_16x16x32_f16(
                    af, bf[tn], acc[tm][tn], 0, 0, 0);
        }
    }

    // wave-uniform tile max for the fp16 rescale
    float lmax = -2.0f;
#pragma unroll
    for (int tm = 0; tm < 4; ++tm)
#pragma unroll
        for (int tn = 0; tn < 4; ++tn)
#pragma unroll
            for (int r = 0; r < 4; ++r) lmax = fmaxf(lmax, acc[tm][tn][r]);
    lmax = fmaxf(lmax, __shfl_xor(lmax, 1));
    lmax = fmaxf(lmax, __shfl_xor(lmax, 2));
    lmax = fmaxf(lmax, __shfl_xor(lmax, 4));
    lmax = fmaxf(lmax, __shfl_xor(lmax, 8));
    lmax = fmaxf(lmax, __shfl_xor(lmax, 16));
    lmax = fmaxf(lmax, __shfl_xor(lmax, 32));
    float s0 = lmax;

    // exp + LDS roundtrip into the xor-permuted (ig,jg) layout, fp16 on read
    half8 Mh[8];
#pragma unroll 1
    for (int round = 0; round < 2; ++round) {
        if ((wave >> 1) == round) {
            float* buf = T[wave & 1];
#pragma unroll
            for (int tm = 0; tm < 4; ++tm)
#pragma unroll
                for (int tn = 0; tn < 4; ++tn)
#pragma unroll
                    for (int r = 0; r < 4; ++r) {
                        int row = tm * 16 + hi4 * 4 + r;
                        int col = tn * 16 + lo16;
                        int sp  = (col & 7) ^ (row >> 3);
                        buf[row * LDP + (col & ~7) + sp] =
                            fexp2((acc[tm][tn][r] - s0) * K_SIM2M);
                    }
        }
        __syncthreads();
        if ((wave >> 1) == round) {
            const float* buf = T[wave & 1];
#pragma unroll
            for (int t = 0; t < 8; ++t) {
                const float* p = buf + (ig * 8 + (jg ^ t)) * LDP + jg * 8;
                float4 m0 = *(const float4*)p;
                float4 m1 = *(const float4*)(p + 4);
                half8 h;
                h[0] = (_Float16)m0.x; h[1] = (_Float16)m0.y;
                h[2] = (_Float16)m0.z; h[3] = (_Float16)m0.w;
                h[4] = (_Float16)m1.x; h[5] = (_Float16)m1.y;
                h[6] = (_Float16)m1.z; h[7] = (_Float16)m1.w;
                Mh[t] = h;
            }
        }
        __syncthreads();
    }

    int p_loc = (q - q0) * 32 + w;
    _Float16* mp = Mg + (size_t)p_loc * 4096 + lane * 8;
#pragma unroll
    for (int t = 0; t < 8; ++t) *(half8*)(mp + (size_t)t * 512) = Mh[t];
    if (lane == 0) s0A[q * 32 + w] = s0;
}

// --------- K4: Sinkhorn + logits. 4 pair-waves per block, 6 waves/EU --------
__global__ void __launch_bounds__(256, 6)
skh_kernel(const _Float16* __restrict__ Mg, const float* __restrict__ s0A,
           const float* __restrict__ a_arr, const float* __restrict__ b_arr,
           float* __restrict__ out, int q0) {
    int wave  = threadIdx.x >> 6;
    int lane  = threadIdx.x & 63;
    int p_loc = blockIdx.x * 4 + wave;
    int q  = q0 + (p_loc >> 5);
    int w  = p_loc & 31;
    int gp = q * 32 + w;
    int ig = lane >> 3;
    int jg = lane & 7;

    const _Float16* mp = Mg + (size_t)p_loc * 4096 + lane * 8;
    half8 Mh[8];
#pragma unroll
    for (int t = 0; t < 8; ++t) Mh[t] = *(const half8*)(mp + (size_t)t * 512);

    float a_own = a_arr[(size_t)gp * 64 + ig * 8 + jg];
    float b_own = b_arr[((size_t)w * 256 + q) * 64 + jg * 8 + ig];

    float wvp[8];
#pragma unroll
    for (int s = 0; s < 8; ++s) wvp[s] = 1.0f;
    float q8[8];
    float w_prev = -1.f;

#pragma unroll 1
    for (int it = 0; it < 100; ++it) {
        float p[8];
#pragma unroll
        for (int t = 0; t < 8; ++t) {
            float s = (float)Mh[t][0] * wvp[0];
#pragma unroll
            for (int c = 1; c < 8; ++c) s = fmaf((float)Mh[t][c], wvp[c], s);
            p[t] = s;
        }
        p[0] += __shfl_xor(p[4], 4); p[1] += __shfl_xor(p[5], 4);
        p[2] += __shfl_xor(p[6], 4); p[3] += __shfl_xor(p[7], 4);
        p[0] += __shfl_xor(p[2], 2); p[1] += __shfl_xor(p[3], 2);
        p[0] += __shfl_xor(p[1], 1);
        float z_own = a_own * fast_rcp(p[0]);
        q8[0] = z_own;
        q8[1] = __shfl_xor(q8[0], 1);
        q8[2] = __shfl_xor(q8[0], 2); q8[3] = __shfl_xor(q8[1], 2);
        q8[4] = __shfl_xor(q8[0], 4); q8[5] = __shfl_xor(q8[1], 4);
        q8[6] = __shfl_xor(q8[2], 4); q8[7] = __shfl_xor(q8[3], 4);
        float cp[8];
#pragma unroll
        for (int s = 0; s < 8; ++s) {
            float v = (float)Mh[0][s] * q8[0];
#pragma unroll
            for (int t = 1; t < 8; ++t) v = fmaf((float)Mh[t][s], q8[t], v);
            cp[s] = v;
        }
        cp[0] += __shfl_xor(cp[4], 32); cp[1] += __shfl_xor(cp[5], 32);
        cp[2] += __shfl_xor(cp[6], 32); cp[3] += __shfl_xor(cp[7], 32);
        cp[0] += __shfl_xor(cp[2], 16); cp[1] += __shfl_xor(cp[3], 16);
        cp[0] += __shfl_xor(cp[1], 8);
        float w_own = b_own * fast_rcp(cp[0]);
        wvp[0] = w_own;
        wvp[1] = __shfl_xor(wvp[0], 8);
        wvp[2] = __shfl_xor(wvp[0], 16); wvp[3] = __shfl_xor(wvp[1], 16);
        wvp[4] = __shfl_xor(wvp[0], 32); wvp[5] = __shfl_xor(wvp[1], 32);
        wvp[6] = __shfl_xor(wvp[2], 32); wvp[7] = __shfl_xor(wvp[3], 32);
        // w stable across all 64 cols -> next z,w identical -> fixed point
        bool same = fabsf(w_own - w_prev) <= 1e-5f * w_own;
        w_prev = w_own;
        if (__all(same)) break;
    }

    float s0 = s0A[gp];
    float s = 0.f;
#pragma unroll
    for (int t = 0; t < 8; ++t)
#pragma unroll
        for (int c = 0; c < 8; ++c) {
            float m    = fmaxf((float)Mh[t][c], 1e-30f);
            float sim  = fmaf(flog2(m), K_M2SIM, s0);
            float flow = q8[t] * m * wvp[c];
            s = fmaf(sim, flow, s);
        }
    s += __shfl_xor(s, 1);  s += __shfl_xor(s, 2);  s += __shfl_xor(s, 4);
    s += __shfl_xor(s, 8);  s += __shfl_xor(s, 16); s += __shfl_xor(s, 32);
    if (lane == 0) out[gp] = s * 0.1953125f;   // 12.5/64
}

// ---------------------------------------------------------------------------
extern "C" void kernel_launch(void* const* d_in, const int* in_sizes, int n_in,
                              void* d_out, int out_size, void* d_ws, size_t ws_size,
                              hipStream_t stream) {
    (void)in_sizes; (void)n_in; (void)out_size;
    const float* support = (const float*)d_in[0];   // 32*512*64
    const float* query   = (const float*)d_in[1];   // 256*512*64

    char* ws = (char*)d_ws;
    _Float16* Uht = (_Float16*)ws;                  // 16 MB
    _Float16* Vht = Uht + 8388608;                  //  2 MB
    float* BpT  = (float*)(Vht + 1048576);          // 64 KB  [512][32]
    float* QpT  = BpT + 16384;                      // 512 KB [512][256]
    float* aA   = QpT + 131072;                     //  2 MB
    float* bA   = aA + 524288;                      //  2 MB
    float* s0A  = bA + 524288;                      // 32 KB
    float* muA  = s0A + 8192;                       // 72 KB [288][64]
    float* nrmA = muA + 18432;                      // 72 KB
    float* Ssc  = nrmA + 18432;                     // ~1 KB [288]
    _Float16* Mg = (_Float16*)(Ssc + 288);          // up to 64 MB
    size_t base = (size_t)((char*)Mg - ws);

    int nsplit = 1;                                 // adaptive to ws_size
    if (ws_size < base + (size_t)64 * 1024 * 1024) nsplit = 2;
    if (ws_size < base + (size_t)32 * 1024 * 1024) nsplit = 4;

    norm_kernel<<<288, 256, 0, stream>>>(support, query, Vht, Uht, BpT, QpT,
                                         muA, nrmA, Ssc);
    marg_kernel<<<512, 256, 0, stream>>>(Uht, Vht, BpT, QpT, muA, nrmA, Ssc,
                                         aA, bA);
    int qchunk = 256 / nsplit;
    for (int s = 0; s < nsplit; ++s) {
        sim_kernel<<<qchunk * 8, 256, 0, stream>>>(Uht, Vht, Mg, s0A,
                                                   s * qchunk, qchunk);
        skh_kernel<<<qchunk * 8, 256, 0, stream>>>(Mg, s0A, aA, bA,
                                                   (float*)d_out, s * qchunk);
    }
}

// Round 8
// 344.552 us; speedup vs baseline: 1.5175x; 1.2094x over previous
//
#include <hip/hip_runtime.h>
#include <math.h>

// ---------------------------------------------------------------------------
// EMD layer (Sinkhorn-OT logits) for MI355X.
// support: [32,512,8,8] f32, query: [256,512,8,8] f32 -> logits [256,32] f32.
//
// R8: Uht/Vht stored in MFMA FRAGMENT ORDER frag[sample][kk][t][lane][8]
//     (kk=K-chunk 0..15, t=row-tile 0..3, lane 0..63, 8 halves). sim's k-loop
//     loads become lane-contiguous 1KB segments (R7 evidence: 64x16B gathers
//     made sim address-divergence-bound at 130us with all pipes ~90% idle).
//     norm writes the layout via re-enumerated LDS-transpose (contiguous 4KB
//     wave stores); marg reads it with c-order preserved (bit-identical).
// ---------------------------------------------------------------------------

#define DEV static __device__ __forceinline__

typedef _Float16 half8 __attribute__((ext_vector_type(8)));
typedef float floatx4 __attribute__((ext_vector_type(4)));

DEV float fast_rcp(float x) {
#if __has_builtin(__builtin_amdgcn_rcpf)
    return __builtin_amdgcn_rcpf(x);
#else
    return 1.0f / x;
#endif
}
DEV float fexp2(float x) {
#if __has_builtin(__builtin_amdgcn_exp2f)
    return __builtin_amdgcn_exp2f(x);
#else
    return exp2f(x);
#endif
}
DEV float flog2(float x) {
#if __has_builtin(__builtin_amdgcn_logf)
    return __builtin_amdgcn_logf(x);
#else
    return log2f(x);
#endif
}

#define K_SIM2M 28.853900817779268f    // 20/ln2 : M = 2^((sim-1)*K_SIM2M)
#define K_M2SIM 0.034657359027997264f  // 0.05*ln2 : sim = 1 + log2(M)*K_M2SIM
#define LDP 68                         // padded LDS row stride (floats)

// ------ K1: center+normalize over C -> fp16 FRAGMENT order, + pool stats ----
// Fragment chunk (kk,t,slot) = channels kk*32+(slot>>4)*8..+8 of node
// t*16+(slot&15), stored at ((kk*4+t)*64+slot)*8 halves.
__global__ void __launch_bounds__(256)
norm_kernel(const float* __restrict__ support, const float* __restrict__ query,
            _Float16* __restrict__ Vht, _Float16* __restrict__ Uht,
            float* __restrict__ BpT, float* __restrict__ QpT,
            float* __restrict__ muA, float* __restrict__ nrmA,
            float* __restrict__ Ssc) {
    __shared__ float red1[4][64];
    __shared__ float red2[4][64];
    __shared__ float muL[64], invL[64];
    __shared__ float tile[128][65];

    int sid = blockIdx.x;             // 0..287
    const float* src;
    _Float16* dst;
    float* poolT;
    int pstride, pidx;
    if (sid < 32) {
        src = support + (size_t)sid * 32768; dst = Vht + (size_t)sid * 32768;
        poolT = BpT; pstride = 32; pidx = sid;
    } else {
        src = query + (size_t)(sid - 32) * 32768; dst = Uht + (size_t)(sid - 32) * 32768;
        poolT = QpT; pstride = 256; pidx = sid - 32;
    }

    int node = threadIdx.x & 63;
    int cq   = threadIdx.x >> 6;      // wave index = c-quarter

    float s1 = 0.f, s2 = 0.f;
#pragma unroll 8
    for (int j = 0; j < 128; ++j) {
        int c = cq * 128 + j;
        float x = src[c * 64 + node];
        s1 += x; s2 += x * x;
        float ps = x;                  // pool: sum over the wave's 64 nodes
        ps += __shfl_xor(ps, 1);  ps += __shfl_xor(ps, 2);  ps += __shfl_xor(ps, 4);
        ps += __shfl_xor(ps, 8);  ps += __shfl_xor(ps, 16); ps += __shfl_xor(ps, 32);
        if (node == 0) poolT[(size_t)c * pstride + pidx] = ps * (1.0f / 64.0f);
    }
    red1[cq][node] = s1;
    red2[cq][node] = s2;
    __syncthreads();
    if (threadIdx.x < 64) {
        float t1 = red1[0][node] + red1[1][node] + red1[2][node] + red1[3][node];
        float t2 = red2[0][node] + red2[1][node] + red2[2][node] + red2[3][node];
        float mu  = t1 * (1.0f / 512.0f);
        float ss  = t2 - 512.0f * mu * mu;
        float nrm = fmaxf(sqrtf(fmaxf(ss, 0.0f)), 1e-8f);
        muL[node]  = mu;
        invL[node] = 1.0f / nrm;
        muA[sid * 64 + node]  = mu;
        nrmA[sid * 64 + node] = nrm;
        float sS = t1;                 // S = sum_c pool[c]
        sS += __shfl_xor(sS, 1);  sS += __shfl_xor(sS, 2);  sS += __shfl_xor(sS, 4);
        sS += __shfl_xor(sS, 8);  sS += __shfl_xor(sS, 16); sS += __shfl_xor(sS, 32);
        if (node == 0) Ssc[sid] = sS * (1.0f / 64.0f);
    }
    __syncthreads();

    for (int ch = 0; ch < 4; ++ch) {          // slab of 128 channels
        float mu = muL[node], inv = invL[node];
#pragma unroll 4
        for (int j = 0; j < 32; ++j) {
            int cl = cq * 32 + j;
            float x = src[(ch * 128 + cl) * 64 + node];
            tile[cl][node] = (x - mu) * inv;
        }
        __syncthreads();
        // write slab's 1024 fragment chunks contiguously: g = chunk id
#pragma unroll
        for (int r = 0; r < 4; ++r) {
            int g    = r * 256 + threadIdx.x;  // kkl*256 + t*64 + slot
            int slot = g & 63;
            int t    = (g >> 6) & 3;
            int kkl  = g >> 8;
            int nd   = t * 16 + (slot & 15);
            int c8   = (kkl << 2) | (slot >> 4);  // tile row block
            half8 v;
#pragma unroll
            for (int i = 0; i < 8; ++i) v[i] = (_Float16)tile[c8 * 8 + i][nd];
            *(half8*)(dst + ((size_t)ch * 1024 + g) * 8) = v;
        }
        __syncthreads();
    }
}

// --------- K2: merged a/b marginals from fragment-order fp16 ----------------
// raw_dot = nrm * <fp16 normalized vec, pooled vec> + mu * S(pooled vec)
__global__ void __launch_bounds__(256)
marg_kernel(const _Float16* __restrict__ Uht, const _Float16* __restrict__ Vht,
            const float* __restrict__ BpT, const float* __restrict__ QpT,
            const float* __restrict__ muA, const float* __restrict__ nrmA,
            const float* __restrict__ Ssc,
            float* __restrict__ a_out, float* __restrict__ b_out) {
    __shared__ __align__(16) float WL[512 * 32];   // [c][k] 64 KB
    __shared__ float Sl[32];
    int lane = threadIdx.x & 63;   // node
    int kq   = threadIdx.x >> 6;   // k = kq*8 .. +7

    const _Float16* src16;
    float mu, nrm;
    if (blockIdx.x < 256) {
        // a-marginals: block per q (XCD-grouped), k enumerates w (32)
        int q = (blockIdx.x & 7) * 32 + (blockIdx.x >> 3);
        for (int t = threadIdx.x; t < 4096; t += 256)
            ((float4*)WL)[t] = ((const float4*)BpT)[t];
        if (threadIdx.x < 32) Sl[threadIdx.x] = Ssc[threadIdx.x];  // S_w
        src16 = Uht + (size_t)q * 32768;
        mu  = muA[(32 + q) * 64 + lane];
        nrm = nrmA[(32 + q) * 64 + lane];
    } else {
        // b-marginals: block per (w, q-group of 32), k enumerates qlocal
        int id = blockIdx.x - 256;
        int w = id >> 3, qg = id & 7;
        for (int t = threadIdx.x; t < 4096; t += 256) {
            int c = t >> 3, k = t & 7;
            ((float4*)WL)[t] = ((const float4*)(QpT + (size_t)c * 256 + qg * 32))[k];
        }
        if (threadIdx.x < 32) Sl[threadIdx.x] = Ssc[32 + qg * 32 + threadIdx.x]; // S'_q
        src16 = Vht + (size_t)w * 32768;
        mu  = muA[w * 64 + lane];
        nrm = nrmA[w * 64 + lane];
    }
    __syncthreads();

    // lane's node-n data: chunk (kk, t=n>>4, slot=(hi<<4)|(n&15)) = c kk*32+hi*8..+8
    int lbase = (lane >> 4) * 64 + (lane & 15);
    float acc[8] = {0, 0, 0, 0, 0, 0, 0, 0};
#pragma unroll 1
    for (int kk = 0; kk < 16; ++kk) {
#pragma unroll
        for (int hi = 0; hi < 4; ++hi) {
            half8 x8 = *(const half8*)(src16 +
                        ((size_t)(kk * 256 + lbase + (hi << 4)) * 8));
            int cb = kk * 32 + hi * 8;
#pragma unroll
            for (int j = 0; j < 8; ++j) {
                float xv = (float)x8[j];
                const float* wl = WL + (cb + j) * 32 + kq * 8;
                float4 b0 = *(const float4*)wl;
                float4 b1 = *(const float4*)(wl + 4);
                acc[0] = fmaf(xv, b0.x, acc[0]); acc[1] = fmaf(xv, b0.y, acc[1]);
                acc[2] = fmaf(xv, b0.z, acc[2]); acc[3] = fmaf(xv, b0.w, acc[3]);
                acc[4] = fmaf(xv, b1.x, acc[4]); acc[5] = fmaf(xv, b1.y, acc[5]);
                acc[6] = fmaf(xv, b1.z, acc[6]); acc[7] = fmaf(xv, b1.w, acc[7]);
            }
        }
    }
#pragma unroll
    for (int k = 0; k < 8; ++k) {
        float raw = fmaf(mu, Sl[kq * 8 + k], nrm * acc[k]);
        float v = fmaxf(raw, 0.0f) + 0.001f;
        v += 1e-5f;
        float s = v;
        s += __shfl_xor(s, 1);  s += __shfl_xor(s, 2);  s += __shfl_xor(s, 4);
        s += __shfl_xor(s, 8);  s += __shfl_xor(s, 16); s += __shfl_xor(s, 32);
        v = v * (64.0f / s);
        if (blockIdx.x < 256) {
            int q = (blockIdx.x & 7) * 32 + (blockIdx.x >> 3), w = kq * 8 + k;
            a_out[((size_t)q * 32 + w) * 64 + lane] = v;
        } else {
            int id = blockIdx.x - 256;
            int w = id >> 3, q = (id & 7) * 32 + kq * 8 + k;
            b_out[((size_t)w * 256 + q) * 64 + lane] = v;
        }
    }
}

// --------- K3: MFMA sim (fragment loads) -> fp16 Gibbs tiles ----------------
// XCD-resident: blockIdx%8 = XCD handles one q-group. Loads lane-contiguous.
__global__ void __launch_bounds__(256, 4)
sim_kernel(const _Float16* __restrict__ Uht, const _Float16* __restrict__ Vht,
           _Float16* __restrict__ Mg, float* __restrict__ s0A,
           int q0, int qchunk) {
    __shared__ __align__(16) float T[2][64 * LDP];   // 34.8 KB

    int x    = blockIdx.x & 7;
    int i    = blockIdx.x >> 3;
    int w    = i & 31;
    int wave = threadIdx.x >> 6;
    int lane = threadIdx.x & 63;
    int q    = q0 + (x * (qchunk >> 5) + (i >> 5)) * 4 + wave;
    int lo16 = lane & 15;
    int hi4  = lane >> 4;
    int ig   = lane >> 3;
    int jg   = lane & 7;

    floatx4 acc[4][4];
#pragma unroll
    for (int tm = 0; tm < 4; ++tm)
#pragma unroll
        for (int tn = 0; tn < 4; ++tn)
            acc[tm][tn] = (floatx4){0.f, 0.f, 0.f, 0.f};

    const _Float16* Abase = Uht + (size_t)q * 32768 + lane * 8;
    const _Float16* Bbase = Vht + (size_t)w * 32768 + lane * 8;
#pragma unroll 1
    for (int kk = 0; kk < 16; ++kk) {
        half8 bf[4];
#pragma unroll
        for (int t = 0; t < 4; ++t)
            bf[t] = *(const half8*)(Bbase + (size_t)(kk * 4 + t) * 512);
#pragma unroll
        for (int tm = 0; tm < 4; ++tm) {
            half8 af = *(const half8*)(Abase + (size_t)(kk * 4 + tm) * 512);
#pragma unroll
            for (int tn = 0; tn < 4; ++tn)
                acc[tm][tn] = __builtin_amdgcn_mfma_f32_16x16x32_f16(
                    af, bf[tn], acc[tm][tn], 0, 0, 0);
        }
    }

    // wave-uniform tile max for the fp16 rescale
    float lmax = -2.0f;
#pragma unroll
    for (int tm = 0; tm < 4; ++tm)
#pragma unroll
        for (int tn = 0; tn < 4; ++tn)
#pragma unroll
            for (int r = 0; r < 4; ++r) lmax = fmaxf(lmax, acc[tm][tn][r]);
    lmax = fmaxf(lmax, __shfl_xor(lmax, 1));
    lmax = fmaxf(lmax, __shfl_xor(lmax, 2));
    lmax = fmaxf(lmax, __shfl_xor(lmax, 4));
    lmax = fmaxf(lmax, __shfl_xor(lmax, 8));
    lmax = fmaxf(lmax, __shfl_xor(lmax, 16));
    lmax = fmaxf(lmax, __shfl_xor(lmax, 32));
    float s0 = lmax;

    // exp + LDS roundtrip into the xor-permuted (ig,jg) layout, fp16 on read
    half8 Mh[8];
#pragma unroll 1
    for (int round = 0; round < 2; ++round) {
        if ((wave >> 1) == round) {
            float* buf = T[wave & 1];
#pragma unroll
            for (int tm = 0; tm < 4; ++tm)
#pragma unroll
                for (int tn = 0; tn < 4; ++tn)
#pragma unroll
                    for (int r = 0; r < 4; ++r) {
                        int row = tm * 16 + hi4 * 4 + r;
                        int col = tn * 16 + lo16;
                        int sp  = (col & 7) ^ (row >> 3);
                        buf[row * LDP + (col & ~7) + sp] =
                            fexp2((acc[tm][tn][r] - s0) * K_SIM2M);
                    }
        }
        __syncthreads();
        if ((wave >> 1) == round) {
            const float* buf = T[wave & 1];
#pragma unroll
            for (int t = 0; t < 8; ++t) {
                const float* p = buf + (ig * 8 + (jg ^ t)) * LDP + jg * 8;
                float4 m0 = *(const float4*)p;
                float4 m1 = *(const float4*)(p + 4);
                half8 h;
                h[0] = (_Float16)m0.x; h[1] = (_Float16)m0.y;
                h[2] = (_Float16)m0.z; h[3] = (_Float16)m0.w;
                h[4] = (_Float16)m1.x; h[5] = (_Float16)m1.y;
                h[6] = (_Float16)m1.z; h[7] = (_Float16)m1.w;
                Mh[t] = h;
            }
        }
        __syncthreads();
    }

    int p_loc = (q - q0) * 32 + w;
    _Float16* mp = Mg + (size_t)p_loc * 4096 + lane * 8;
#pragma unroll
    for (int t = 0; t < 8; ++t) *(half8*)(mp + (size_t)t * 512) = Mh[t];
    if (lane == 0) s0A[q * 32 + w] = s0;
}

// --------- K4: Sinkhorn + logits. 4 pair-waves per block, 6 waves/EU --------
__global__ void __launch_bounds__(256, 6)
skh_kernel(const _Float16* __restrict__ Mg, const float* __restrict__ s0A,
           const float* __restrict__ a_arr, const float* __restrict__ b_arr,
           float* __restrict__ out, int q0) {
    int wave  = threadIdx.x >> 6;
    int lane  = threadIdx.x & 63;
    int p_loc = blockIdx.x * 4 + wave;
    int q  = q0 + (p_loc >> 5);
    int w  = p_loc & 31;
    int gp = q * 32 + w;
    int ig = lane >> 3;
    int jg = lane & 7;

    const _Float16* mp = Mg + (size_t)p_loc * 4096 + lane * 8;
    half8 Mh[8];
#pragma unroll
    for (int t = 0; t < 8; ++t) Mh[t] = *(const half8*)(mp + (size_t)t * 512);

    float a_own = a_arr[(size_t)gp * 64 + ig * 8 + jg];
    float b_own = b_arr[((size_t)w * 256 + q) * 64 + jg * 8 + ig];

    float wvp[8];
#pragma unroll
    for (int s = 0; s < 8; ++s) wvp[s] = 1.0f;
    float q8[8];
    float w_prev = -1.f;

#pragma unroll 1
    for (int it = 0; it < 100; ++it) {
        float p[8];
#pragma unroll
        for (int t = 0; t < 8; ++t) {
            float s = (float)Mh[t][0] * wvp[0];
#pragma unroll
            for (int c = 1; c < 8; ++c) s = fmaf((float)Mh[t][c], wvp[c], s);
            p[t] = s;
        }
        p[0] += __shfl_xor(p[4], 4); p[1] += __shfl_xor(p[5], 4);
        p[2] += __shfl_xor(p[6], 4); p[3] += __shfl_xor(p[7], 4);
        p[0] += __shfl_xor(p[2], 2); p[1] += __shfl_xor(p[3], 2);
        p[0] += __shfl_xor(p[1], 1);
        float z_own = a_own * fast_rcp(p[0]);
        q8[0] = z_own;
        q8[1] = __shfl_xor(q8[0], 1);
        q8[2] = __shfl_xor(q8[0], 2); q8[3] = __shfl_xor(q8[1], 2);
        q8[4] = __shfl_xor(q8[0], 4); q8[5] = __shfl_xor(q8[1], 4);
        q8[6] = __shfl_xor(q8[2], 4); q8[7] = __shfl_xor(q8[3], 4);
        float cp[8];
#pragma unroll
        for (int s = 0; s < 8; ++s) {
            float v = (float)Mh[0][s] * q8[0];
#pragma unroll
            for (int t = 1; t < 8; ++t) v = fmaf((float)Mh[t][s], q8[t], v);
            cp[s] = v;
        }
        cp[0] += __shfl_xor(cp[4], 32); cp[1] += __shfl_xor(cp[5], 32);
        cp[2] += __shfl_xor(cp[6], 32); cp[3] += __shfl_xor(cp[7], 32);
        cp[0] += __shfl_xor(cp[2], 16); cp[1] += __shfl_xor(cp[3], 16);
        cp[0] += __shfl_xor(cp[1], 8);
        float w_own = b_own * fast_rcp(cp[0]);
        wvp[0] = w_own;
        wvp[1] = __shfl_xor(wvp[0], 8);
        wvp[2] = __shfl_xor(wvp[0], 16); wvp[3] = __shfl_xor(wvp[1], 16);
        wvp[4] = __shfl_xor(wvp[0], 32); wvp[5] = __shfl_xor(wvp[1], 32);
        wvp[6] = __shfl_xor(wvp[2], 32); wvp[7] = __shfl_xor(wvp[3], 32);
        // w stable across all 64 cols -> next z,w identical -> fixed point
        bool same = fabsf(w_own - w_prev) <= 1e-5f * w_own;
        w_prev = w_own;
        if (__all(same)) break;
    }

    float s0 = s0A[gp];
    float s = 0.f;
#pragma unroll
    for (int t = 0; t < 8; ++t)
#pragma unroll
        for (int c = 0; c < 8; ++c) {
            float m    = fmaxf((float)Mh[t][c], 1e-30f);
            float sim  = fmaf(flog2(m), K_M2SIM, s0);
            float flow = q8[t] * m * wvp[c];
            s = fmaf(sim, flow, s);
        }
    s += __shfl_xor(s, 1);  s += __shfl_xor(s, 2);  s += __shfl_xor(s, 4);
    s += __shfl_xor(s, 8);  s += __shfl_xor(s, 16); s += __shfl_xor(s, 32);
    if (lane == 0) out[gp] = s * 0.1953125f;   // 12.5/64
}

// ---------------------------------------------------------------------------
extern "C" void kernel_launch(void* const* d_in, const int* in_sizes, int n_in,
                              void* d_out, int out_size, void* d_ws, size_t ws_size,
                              hipStream_t stream) {
    (void)in_sizes; (void)n_in; (void)out_size;
    const float* support = (const float*)d_in[0];   // 32*512*64
    const float* query   = (const float*)d_in[1];   // 256*512*64

    char* ws = (char*)d_ws;
    _Float16* Uht = (_Float16*)ws;                  // 16 MB (fragment order)
    _Float16* Vht = Uht + 8388608;                  //  2 MB (fragment order)
    float* BpT  = (float*)(Vht + 1048576);          // 64 KB  [512][32]
    float* QpT  = BpT + 16384;                      // 512 KB [512][256]
    float* aA   = QpT + 131072;                     //  2 MB
    float* bA   = aA + 524288;                      //  2 MB
    float* s0A  = bA + 524288;                      // 32 KB
    float* muA  = s0A + 8192;                       // 72 KB [288][64]
    float* nrmA = muA + 18432;                      // 72 KB
    float* Ssc  = nrmA + 18432;                     // ~1 KB [288]
    _Float16* Mg = (_Float16*)(Ssc + 288);          // up to 64 MB
    size_t base = (size_t)((char*)Mg - ws);

    int nsplit = 1;                                 // adaptive to ws_size
    if (ws_size < base + (size_t)64 * 1024 * 1024) nsplit = 2;
    if (ws_size < base + (size_t)32 * 1024 * 1024) nsplit = 4;

    norm_kernel<<<288, 256, 0, stream>>>(support, query, Vht, Uht, BpT, QpT,
                                         muA, nrmA, Ssc);
    marg_kernel<<<512, 256, 0, stream>>>(Uht, Vht, BpT, QpT, muA, nrmA, Ssc,
                                         aA, bA);
    int qchunk = 256 / nsplit;
    for (int s = 0; s < nsplit; ++s) {
        sim_kernel<<<qchunk * 8, 256, 0, stream>>>(Uht, Vht, Mg, s0A,
                                                   s * qchunk, qchunk);
        skh_kernel<<<qchunk * 8, 256, 0, stream>>>(Mg, s0A, aA, bA,
                                                   (float*)d_out, s * qchunk);
    }
}

// Round 9
// 253.051 us; speedup vs baseline: 2.0662x; 1.3616x over previous
//
#include <hip/hip_runtime.h>
#include <math.h>

// ---------------------------------------------------------------------------
// EMD layer (Sinkhorn-OT logits) for MI355X.
// support: [32,512,8,8] f32, query: [256,512,8,8] f32 -> logits [256,32] f32.
//
// R9: skh launch_bounds (256,6)->(256,4). R8 profile showed skh VGPR=40 with
//     147MB scratch writes: at an ~85-reg budget the allocator spills Mh(32)
//     +wvp/q8(16)+temps. R4's fused kernel proved this exact loop compiles
//     clean (VGPR 64, WRITE 0.25MB) at a 128-reg budget; 16 waves/CU unspilled
//     beats 24 waves/CU through scratch. All else identical to R8.
// ---------------------------------------------------------------------------

#define DEV static __device__ __forceinline__

typedef _Float16 half8 __attribute__((ext_vector_type(8)));
typedef float floatx4 __attribute__((ext_vector_type(4)));

DEV float fast_rcp(float x) {
#if __has_builtin(__builtin_amdgcn_rcpf)
    return __builtin_amdgcn_rcpf(x);
#else
    return 1.0f / x;
#endif
}
DEV float fexp2(float x) {
#if __has_builtin(__builtin_amdgcn_exp2f)
    return __builtin_amdgcn_exp2f(x);
#else
    return exp2f(x);
#endif
}
DEV float flog2(float x) {
#if __has_builtin(__builtin_amdgcn_logf)
    return __builtin_amdgcn_logf(x);
#else
    return log2f(x);
#endif
}

#define K_SIM2M 28.853900817779268f    // 20/ln2 : M = 2^((sim-1)*K_SIM2M)
#define K_M2SIM 0.034657359027997264f  // 0.05*ln2 : sim = 1 + log2(M)*K_M2SIM
#define LDP 68                         // padded LDS row stride (floats)

// ------ K1: center+normalize over C -> fp16 FRAGMENT order, + pool stats ----
// Fragment chunk (kk,t,slot) = channels kk*32+(slot>>4)*8..+8 of node
// t*16+(slot&15), stored at ((kk*4+t)*64+slot)*8 halves.
__global__ void __launch_bounds__(256)
norm_kernel(const float* __restrict__ support, const float* __restrict__ query,
            _Float16* __restrict__ Vht, _Float16* __restrict__ Uht,
            float* __restrict__ BpT, float* __restrict__ QpT,
            float* __restrict__ muA, float* __restrict__ nrmA,
            float* __restrict__ Ssc) {
    __shared__ float red1[4][64];
    __shared__ float red2[4][64];
    __shared__ float muL[64], invL[64];
    __shared__ float tile[128][65];

    int sid = blockIdx.x;             // 0..287
    const float* src;
    _Float16* dst;
    float* poolT;
    int pstride, pidx;
    if (sid < 32) {
        src = support + (size_t)sid * 32768; dst = Vht + (size_t)sid * 32768;
        poolT = BpT; pstride = 32; pidx = sid;
    } else {
        src = query + (size_t)(sid - 32) * 32768; dst = Uht + (size_t)(sid - 32) * 32768;
        poolT = QpT; pstride = 256; pidx = sid - 32;
    }

    int node = threadIdx.x & 63;
    int cq   = threadIdx.x >> 6;      // wave index = c-quarter

    float s1 = 0.f, s2 = 0.f;
#pragma unroll 8
    for (int j = 0; j < 128; ++j) {
        int c = cq * 128 + j;
        float x = src[c * 64 + node];
        s1 += x; s2 += x * x;
        float ps = x;                  // pool: sum over the wave's 64 nodes
        ps += __shfl_xor(ps, 1);  ps += __shfl_xor(ps, 2);  ps += __shfl_xor(ps, 4);
        ps += __shfl_xor(ps, 8);  ps += __shfl_xor(ps, 16); ps += __shfl_xor(ps, 32);
        if (node == 0) poolT[(size_t)c * pstride + pidx] = ps * (1.0f / 64.0f);
    }
    red1[cq][node] = s1;
    red2[cq][node] = s2;
    __syncthreads();
    if (threadIdx.x < 64) {
        float t1 = red1[0][node] + red1[1][node] + red1[2][node] + red1[3][node];
        float t2 = red2[0][node] + red2[1][node] + red2[2][node] + red2[3][node];
        float mu  = t1 * (1.0f / 512.0f);
        float ss  = t2 - 512.0f * mu * mu;
        float nrm = fmaxf(sqrtf(fmaxf(ss, 0.0f)), 1e-8f);
        muL[node]  = mu;
        invL[node] = 1.0f / nrm;
        muA[sid * 64 + node]  = mu;
        nrmA[sid * 64 + node] = nrm;
        float sS = t1;                 // S = sum_c pool[c]
        sS += __shfl_xor(sS, 1);  sS += __shfl_xor(sS, 2);  sS += __shfl_xor(sS, 4);
        sS += __shfl_xor(sS, 8);  sS += __shfl_xor(sS, 16); sS += __shfl_xor(sS, 32);
        if (node == 0) Ssc[sid] = sS * (1.0f / 64.0f);
    }
    __syncthreads();

    for (int ch = 0; ch < 4; ++ch) {          // slab of 128 channels
        float mu = muL[node], inv = invL[node];
#pragma unroll 4
        for (int j = 0; j < 32; ++j) {
            int cl = cq * 32 + j;
            float x = src[(ch * 128 + cl) * 64 + node];
            tile[cl][node] = (x - mu) * inv;
        }
        __syncthreads();
        // write slab's 1024 fragment chunks contiguously: g = chunk id
#pragma unroll
        for (int r = 0; r < 4; ++r) {
            int g    = r * 256 + threadIdx.x;  // kkl*256 + t*64 + slot
            int slot = g & 63;
            int t    = (g >> 6) & 3;
            int kkl  = g >> 8;
            int nd   = t * 16 + (slot & 15);
            int c8   = (kkl << 2) | (slot >> 4);  // tile row block
            half8 v;
#pragma unroll
            for (int i = 0; i < 8; ++i) v[i] = (_Float16)tile[c8 * 8 + i][nd];
            *(half8*)(dst + ((size_t)ch * 1024 + g) * 8) = v;
        }
        __syncthreads();
    }
}

// --------- K2: merged a/b marginals from fragment-order fp16 ----------------
// raw_dot = nrm * <fp16 normalized vec, pooled vec> + mu * S(pooled vec)
__global__ void __launch_bounds__(256)
marg_kernel(const _Float16* __restrict__ Uht, const _Float16* __restrict__ Vht,
            const float* __restrict__ BpT, const float* __restrict__ QpT,
            const float* __restrict__ muA, const float* __restrict__ nrmA,
            const float* __restrict__ Ssc,
            float* __restrict__ a_out, float* __restrict__ b_out) {
    __shared__ __align__(16) float WL[512 * 32];   // [c][k] 64 KB
    __shared__ float Sl[32];
    int lane = threadIdx.x & 63;   // node
    int kq   = threadIdx.x >> 6;   // k = kq*8 .. +7

    const _Float16* src16;
    float mu, nrm;
    if (blockIdx.x < 256) {
        // a-marginals: block per q (XCD-grouped), k enumerates w (32)
        int q = (blockIdx.x & 7) * 32 + (blockIdx.x >> 3);
        for (int t = threadIdx.x; t < 4096; t += 256)
            ((float4*)WL)[t] = ((const float4*)BpT)[t];
        if (threadIdx.x < 32) Sl[threadIdx.x] = Ssc[threadIdx.x];  // S_w
        src16 = Uht + (size_t)q * 32768;
        mu  = muA[(32 + q) * 64 + lane];
        nrm = nrmA[(32 + q) * 64 + lane];
    } else {
        // b-marginals: block per (w, q-group of 32), k enumerates qlocal
        int id = blockIdx.x - 256;
        int w = id >> 3, qg = id & 7;
        for (int t = threadIdx.x; t < 4096; t += 256) {
            int c = t >> 3, k = t & 7;
            ((float4*)WL)[t] = ((const float4*)(QpT + (size_t)c * 256 + qg * 32))[k];
        }
        if (threadIdx.x < 32) Sl[threadIdx.x] = Ssc[32 + qg * 32 + threadIdx.x]; // S'_q
        src16 = Vht + (size_t)w * 32768;
        mu  = muA[w * 64 + lane];
        nrm = nrmA[w * 64 + lane];
    }
    __syncthreads();

    // lane's node-n data: chunk (kk, t=n>>4, slot=(hi<<4)|(n&15)) = c kk*32+hi*8..+8
    int lbase = (lane >> 4) * 64 + (lane & 15);
    float acc[8] = {0, 0, 0, 0, 0, 0, 0, 0};
#pragma unroll 1
    for (int kk = 0; kk < 16; ++kk) {
#pragma unroll
        for (int hi = 0; hi < 4; ++hi) {
            half8 x8 = *(const half8*)(src16 +
                        ((size_t)(kk * 256 + lbase + (hi << 4)) * 8));
            int cb = kk * 32 + hi * 8;
#pragma unroll
            for (int j = 0; j < 8; ++j) {
                float xv = (float)x8[j];
                const float* wl = WL + (cb + j) * 32 + kq * 8;
                float4 b0 = *(const float4*)wl;
                float4 b1 = *(const float4*)(wl + 4);
                acc[0] = fmaf(xv, b0.x, acc[0]); acc[1] = fmaf(xv, b0.y, acc[1]);
                acc[2] = fmaf(xv, b0.z, acc[2]); acc[3] = fmaf(xv, b0.w, acc[3]);
                acc[4] = fmaf(xv, b1.x, acc[4]); acc[5] = fmaf(xv, b1.y, acc[5]);
                acc[6] = fmaf(xv, b1.z, acc[6]); acc[7] = fmaf(xv, b1.w, acc[7]);
            }
        }
    }
#pragma unroll
    for (int k = 0; k < 8; ++k) {
        float raw = fmaf(mu, Sl[kq * 8 + k], nrm * acc[k]);
        float v = fmaxf(raw, 0.0f) + 0.001f;
        v += 1e-5f;
        float s = v;
        s += __shfl_xor(s, 1);  s += __shfl_xor(s, 2);  s += __shfl_xor(s, 4);
        s += __shfl_xor(s, 8);  s += __shfl_xor(s, 16); s += __shfl_xor(s, 32);
        v = v * (64.0f / s);
        if (blockIdx.x < 256) {
            int q = (blockIdx.x & 7) * 32 + (blockIdx.x >> 3), w = kq * 8 + k;
            a_out[((size_t)q * 32 + w) * 64 + lane] = v;
        } else {
            int id = blockIdx.x - 256;
            int w = id >> 3, q = (id & 7) * 32 + kq * 8 + k;
            b_out[((size_t)w * 256 + q) * 64 + lane] = v;
        }
    }
}

// --------- K3: MFMA sim (fragment loads) -> fp16 Gibbs tiles ----------------
// XCD-resident: blockIdx%8 = XCD handles one q-group. Loads lane-contiguous.
__global__ void __launch_bounds__(256, 4)
sim_kernel(const _Float16* __restrict__ Uht, const _Float16* __restrict__ Vht,
           _Float16* __restrict__ Mg, float* __restrict__ s0A,
           int q0, int qchunk) {
    __shared__ __align__(16) float T[2][64 * LDP];   // 34.8 KB

    int x    = blockIdx.x & 7;
    int i    = blockIdx.x >> 3;
    int w    = i & 31;
    int wave = threadIdx.x >> 6;
    int lane = threadIdx.x & 63;
    int q    = q0 + (x * (qchunk >> 5) + (i >> 5)) * 4 + wave;
    int lo16 = lane & 15;
    int hi4  = lane >> 4;
    int ig   = lane >> 3;
    int jg   = lane & 7;

    floatx4 acc[4][4];
#pragma unroll
    for (int tm = 0; tm < 4; ++tm)
#pragma unroll
        for (int tn = 0; tn < 4; ++tn)
            acc[tm][tn] = (floatx4){0.f, 0.f, 0.f, 0.f};

    const _Float16* Abase = Uht + (size_t)q * 32768 + lane * 8;
    const _Float16* Bbase = Vht + (size_t)w * 32768 + lane * 8;
#pragma unroll 1
    for (int kk = 0; kk < 16; ++kk) {
        half8 bf[4];
#pragma unroll
        for (int t = 0; t < 4; ++t)
            bf[t] = *(const half8*)(Bbase + (size_t)(kk * 4 + t) * 512);
#pragma unroll
        for (int tm = 0; tm < 4; ++tm) {
            half8 af = *(const half8*)(Abase + (size_t)(kk * 4 + tm) * 512);
#pragma unroll
            for (int tn = 0; tn < 4; ++tn)
                acc[tm][tn] = __builtin_amdgcn_mfma_f32_16x16x32_f16(
                    af, bf[tn], acc[tm][tn], 0, 0, 0);
        }
    }

    // wave-uniform tile max for the fp16 rescale
    float lmax = -2.0f;
#pragma unroll
    for (int tm = 0; tm < 4; ++tm)
#pragma unroll
        for (int tn = 0; tn < 4; ++tn)
#pragma unroll
            for (int r = 0; r < 4; ++r) lmax = fmaxf(lmax, acc[tm][tn][r]);
    lmax = fmaxf(lmax, __shfl_xor(lmax, 1));
    lmax = fmaxf(lmax, __shfl_xor(lmax, 2));
    lmax = fmaxf(lmax, __shfl_xor(lmax, 4));
    lmax = fmaxf(lmax, __shfl_xor(lmax, 8));
    lmax = fmaxf(lmax, __shfl_xor(lmax, 16));
    lmax = fmaxf(lmax, __shfl_xor(lmax, 32));
    float s0 = lmax;

    // exp + LDS roundtrip into the xor-permuted (ig,jg) layout, fp16 on read
    half8 Mh[8];
#pragma unroll 1
    for (int round = 0; round < 2; ++round) {
        if ((wave >> 1) == round) {
            float* buf = T[wave & 1];
#pragma unroll
            for (int tm = 0; tm < 4; ++tm)
#pragma unroll
                for (int tn = 0; tn < 4; ++tn)
#pragma unroll
                    for (int r = 0; r < 4; ++r) {
                        int row = tm * 16 + hi4 * 4 + r;
                        int col = tn * 16 + lo16;
                        int sp  = (col & 7) ^ (row >> 3);
                        buf[row * LDP + (col & ~7) + sp] =
                            fexp2((acc[tm][tn][r] - s0) * K_SIM2M);
                    }
        }
        __syncthreads();
        if ((wave >> 1) == round) {
            const float* buf = T[wave & 1];
#pragma unroll
            for (int t = 0; t < 8; ++t) {
                const float* p = buf + (ig * 8 + (jg ^ t)) * LDP + jg * 8;
                float4 m0 = *(const float4*)p;
                float4 m1 = *(const float4*)(p + 4);
                half8 h;
                h[0] = (_Float16)m0.x; h[1] = (_Float16)m0.y;
                h[2] = (_Float16)m0.z; h[3] = (_Float16)m0.w;
                h[4] = (_Float16)m1.x; h[5] = (_Float16)m1.y;
                h[6] = (_Float16)m1.z; h[7] = (_Float16)m1.w;
                Mh[t] = h;
            }
        }
        __syncthreads();
    }

    int p_loc = (q - q0) * 32 + w;
    _Float16* mp = Mg + (size_t)p_loc * 4096 + lane * 8;
#pragma unroll
    for (int t = 0; t < 8; ++t) *(half8*)(mp + (size_t)t * 512) = Mh[t];
    if (lane == 0) s0A[q * 32 + w] = s0;
}

// --------- K4: Sinkhorn + logits. 4 pair-waves per block, 4 waves/EU --------
// (256,4): 128-reg budget. R4 evidence: this loop compiles to ~64 VGPR clean;
// (256,6)'s 85-reg budget spilled Mh to scratch (R8: 147MB WRITE, VGPR=40).
__global__ void __launch_bounds__(256, 4)
skh_kernel(const _Float16* __restrict__ Mg, const float* __restrict__ s0A,
           const float* __restrict__ a_arr, const float* __restrict__ b_arr,
           float* __restrict__ out, int q0) {
    int wave  = threadIdx.x >> 6;
    int lane  = threadIdx.x & 63;
    int p_loc = blockIdx.x * 4 + wave;
    int q  = q0 + (p_loc >> 5);
    int w  = p_loc & 31;
    int gp = q * 32 + w;
    int ig = lane >> 3;
    int jg = lane & 7;

    const _Float16* mp = Mg + (size_t)p_loc * 4096 + lane * 8;
    half8 Mh[8];
#pragma unroll
    for (int t = 0; t < 8; ++t) Mh[t] = *(const half8*)(mp + (size_t)t * 512);

    float a_own = a_arr[(size_t)gp * 64 + ig * 8 + jg];
    float b_own = b_arr[((size_t)w * 256 + q) * 64 + jg * 8 + ig];

    float wvp[8];
#pragma unroll
    for (int s = 0; s < 8; ++s) wvp[s] = 1.0f;
    float q8[8];
    float w_prev = -1.f;

#pragma unroll 1
    for (int it = 0; it < 100; ++it) {
        float p[8];
#pragma unroll
        for (int t = 0; t < 8; ++t) {
            float s = (float)Mh[t][0] * wvp[0];
#pragma unroll
            for (int c = 1; c < 8; ++c) s = fmaf((float)Mh[t][c], wvp[c], s);
            p[t] = s;
        }
        p[0] += __shfl_xor(p[4], 4); p[1] += __shfl_xor(p[5], 4);
        p[2] += __shfl_xor(p[6], 4); p[3] += __shfl_xor(p[7], 4);
        p[0] += __shfl_xor(p[2], 2); p[1] += __shfl_xor(p[3], 2);
        p[0] += __shfl_xor(p[1], 1);
        float z_own = a_own * fast_rcp(p[0]);
        q8[0] = z_own;
        q8[1] = __shfl_xor(q8[0], 1);
        q8[2] = __shfl_xor(q8[0], 2); q8[3] = __shfl_xor(q8[1], 2);
        q8[4] = __shfl_xor(q8[0], 4); q8[5] = __shfl_xor(q8[1], 4);
        q8[6] = __shfl_xor(q8[2], 4); q8[7] = __shfl_xor(q8[3], 4);
        float cp[8];
#pragma unroll
        for (int s = 0; s < 8; ++s) {
            float v = (float)Mh[0][s] * q8[0];
#pragma unroll
            for (int t = 1; t < 8; ++t) v = fmaf((float)Mh[t][s], q8[t], v);
            cp[s] = v;
        }
        cp[0] += __shfl_xor(cp[4], 32); cp[1] += __shfl_xor(cp[5], 32);
        cp[2] += __shfl_xor(cp[6], 32); cp[3] += __shfl_xor(cp[7], 32);
        cp[0] += __shfl_xor(cp[2], 16); cp[1] += __shfl_xor(cp[3], 16);
        cp[0] += __shfl_xor(cp[1], 8);
        float w_own = b_own * fast_rcp(cp[0]);
        wvp[0] = w_own;
        wvp[1] = __shfl_xor(wvp[0], 8);
        wvp[2] = __shfl_xor(wvp[0], 16); wvp[3] = __shfl_xor(wvp[1], 16);
        wvp[4] = __shfl_xor(wvp[0], 32); wvp[5] = __shfl_xor(wvp[1], 32);
        wvp[6] = __shfl_xor(wvp[2], 32); wvp[7] = __shfl_xor(wvp[3], 32);
        // w stable across all 64 cols -> next z,w identical -> fixed point
        bool same = fabsf(w_own - w_prev) <= 1e-5f * w_own;
        w_prev = w_own;
        if (__all(same)) break;
    }

    float s0 = s0A[gp];
    float s = 0.f;
#pragma unroll
    for (int t = 0; t < 8; ++t)
#pragma unroll
        for (int c = 0; c < 8; ++c) {
            float m    = fmaxf((float)Mh[t][c], 1e-30f);
            float sim  = fmaf(flog2(m), K_M2SIM, s0);
            float flow = q8[t] * m * wvp[c];
            s = fmaf(sim, flow, s);
        }
    s += __shfl_xor(s, 1);  s += __shfl_xor(s, 2);  s += __shfl_xor(s, 4);
    s += __shfl_xor(s, 8);  s += __shfl_xor(s, 16); s += __shfl_xor(s, 32);
    if (lane == 0) out[gp] = s * 0.1953125f;   // 12.5/64
}

// ---------------------------------------------------------------------------
extern "C" void kernel_launch(void* const* d_in, const int* in_sizes, int n_in,
                              void* d_out, int out_size, void* d_ws, size_t ws_size,
                              hipStream_t stream) {
    (void)in_sizes; (void)n_in; (void)out_size;
    const float* support = (const float*)d_in[0];   // 32*512*64
    const float* query   = (const float*)d_in[1];   // 256*512*64

    char* ws = (char*)d_ws;
    _Float16* Uht = (_Float16*)ws;                  // 16 MB (fragment order)
    _Float16* Vht = Uht + 8388608;                  //  2 MB (fragment order)
    float* BpT  = (float*)(Vht + 1048576);          // 64 KB  [512][32]
    float* QpT  = BpT + 16384;                      // 512 KB [512][256]
    float* aA   = QpT + 131072;                     //  2 MB
    float* bA   = aA + 524288;                      //  2 MB
    float* s0A  = bA + 524288;                      // 32 KB
    float* muA  = s0A + 8192;                       // 72 KB [288][64]
    float* nrmA = muA + 18432;                      // 72 KB
    float* Ssc  = nrmA + 18432;                     // ~1 KB [288]
    _Float16* Mg = (_Float16*)(Ssc + 288);          // up to 64 MB
    size_t base = (size_t)((char*)Mg - ws);

    int nsplit = 1;                                 // adaptive to ws_size
    if (ws_size < base + (size_t)64 * 1024 * 1024) nsplit = 2;
    if (ws_size < base + (size_t)32 * 1024 * 1024) nsplit = 4;

    norm_kernel<<<288, 256, 0, stream>>>(support, query, Vht, Uht, BpT, QpT,
                                         muA, nrmA, Ssc);
    marg_kernel<<<512, 256, 0, stream>>>(Uht, Vht, BpT, QpT, muA, nrmA, Ssc,
                                         aA, bA);
    int qchunk = 256 / nsplit;
    for (int s = 0; s < nsplit; ++s) {
        sim_kernel<<<qchunk * 8, 256, 0, stream>>>(Uht, Vht, Mg, s0A,
                                                   s * qchunk, qchunk);
        skh_kernel<<<qchunk * 8, 256, 0, stream>>>(Mg, s0A, aA, bA,
                                                   (float*)d_out, s * qchunk);
    }
}

// Round 10
// 204.301 us; speedup vs baseline: 2.5592x; 1.2386x over previous
//
#include <hip/hip_runtime.h>
#include <math.h>

// ---------------------------------------------------------------------------
// EMD layer (Sinkhorn-OT logits) for MI355X.
// support: [32,512,8,8] f32, query: [256,512,8,8] f32 -> logits [256,32] f32.
//
// R10: norm_kernel widened 256 -> 1024 threads/block (grid stays 288).
//      R9 profile: norm 90us, VALUBusy 4.8%, Occupancy 9.5% -- 1.1 wave/SIMD
//      latency-bound streaming. 16 waves/block restores ~4 waves/SIMD.
//      Stats: 16 waves x 32 channels; fragment-write: 1 chunk/thread/slab.
//      marg/sim/skh byte-identical to R9.
// ---------------------------------------------------------------------------

#define DEV static __device__ __forceinline__

typedef _Float16 half8 __attribute__((ext_vector_type(8)));
typedef float floatx4 __attribute__((ext_vector_type(4)));

DEV float fast_rcp(float x) {
#if __has_builtin(__builtin_amdgcn_rcpf)
    return __builtin_amdgcn_rcpf(x);
#else
    return 1.0f / x;
#endif
}
DEV float fexp2(float x) {
#if __has_builtin(__builtin_amdgcn_exp2f)
    return __builtin_amdgcn_exp2f(x);
#else
    return exp2f(x);
#endif
}
DEV float flog2(float x) {
#if __has_builtin(__builtin_amdgcn_logf)
    return __builtin_amdgcn_logf(x);
#else
    return log2f(x);
#endif
}

#define K_SIM2M 28.853900817779268f    // 20/ln2 : M = 2^((sim-1)*K_SIM2M)
#define K_M2SIM 0.034657359027997264f  // 0.05*ln2 : sim = 1 + log2(M)*K_M2SIM
#define LDP 68                         // padded LDS row stride (floats)

// ------ K1: center+normalize over C -> fp16 FRAGMENT order, + pool stats ----
// 1024 threads: 16 waves. Fragment chunk (kk,t,slot) = channels
// kk*32+(slot>>4)*8..+8 of node t*16+(slot&15), at ((kk*4+t)*64+slot)*8 halves.
__global__ void __launch_bounds__(1024, 1)
norm_kernel(const float* __restrict__ support, const float* __restrict__ query,
            _Float16* __restrict__ Vht, _Float16* __restrict__ Uht,
            float* __restrict__ BpT, float* __restrict__ QpT,
            float* __restrict__ muA, float* __restrict__ nrmA,
            float* __restrict__ Ssc) {
    __shared__ float red1[16][64];
    __shared__ float red2[16][64];
    __shared__ float muL[64], invL[64];
    __shared__ float tile[128][65];

    int sid = blockIdx.x;             // 0..287
    const float* src;
    _Float16* dst;
    float* poolT;
    int pstride, pidx;
    if (sid < 32) {
        src = support + (size_t)sid * 32768; dst = Vht + (size_t)sid * 32768;
        poolT = BpT; pstride = 32; pidx = sid;
    } else {
        src = query + (size_t)(sid - 32) * 32768; dst = Uht + (size_t)(sid - 32) * 32768;
        poolT = QpT; pstride = 256; pidx = sid - 32;
    }

    int node = threadIdx.x & 63;
    int cq   = threadIdx.x >> 6;      // wave index 0..15

    // ---- stats pass: each wave handles 32 channels ----
    float s1 = 0.f, s2 = 0.f;
#pragma unroll 8
    for (int j = 0; j < 32; ++j) {
        int c = cq * 32 + j;
        float x = src[c * 64 + node];
        s1 += x; s2 += x * x;
        float ps = x;                  // pool: sum over the wave's 64 nodes
        ps += __shfl_xor(ps, 1);  ps += __shfl_xor(ps, 2);  ps += __shfl_xor(ps, 4);
        ps += __shfl_xor(ps, 8);  ps += __shfl_xor(ps, 16); ps += __shfl_xor(ps, 32);
        if (node == 0) poolT[(size_t)c * pstride + pidx] = ps * (1.0f / 64.0f);
    }
    red1[cq][node] = s1;
    red2[cq][node] = s2;
    __syncthreads();
    if (threadIdx.x < 64) {
        float t1 = 0.f, t2 = 0.f;
#pragma unroll
        for (int k = 0; k < 16; ++k) { t1 += red1[k][node]; t2 += red2[k][node]; }
        float mu  = t1 * (1.0f / 512.0f);
        float ss  = t2 - 512.0f * mu * mu;
        float nrm = fmaxf(sqrtf(fmaxf(ss, 0.0f)), 1e-8f);
        muL[node]  = mu;
        invL[node] = 1.0f / nrm;
        muA[sid * 64 + node]  = mu;
        nrmA[sid * 64 + node] = nrm;
        float sS = t1;                 // S = sum_c pool[c]
        sS += __shfl_xor(sS, 1);  sS += __shfl_xor(sS, 2);  sS += __shfl_xor(sS, 4);
        sS += __shfl_xor(sS, 8);  sS += __shfl_xor(sS, 16); sS += __shfl_xor(sS, 32);
        if (node == 0) Ssc[sid] = sS * (1.0f / 64.0f);
    }
    __syncthreads();

    // ---- normalize + fragment-order write, slab = 128 channels ----
    float mu = muL[node], inv = invL[node];
    for (int ch = 0; ch < 4; ++ch) {
#pragma unroll
        for (int j = 0; j < 8; ++j) {
            int cl = cq * 8 + j;       // 16 waves x 8 = 128 channels
            float x = src[(ch * 128 + cl) * 64 + node];
            tile[cl][node] = (x - mu) * inv;
        }
        __syncthreads();
        // 1024 fragment chunks per slab: exactly one per thread
        {
            int g    = threadIdx.x;    // kkl*256 + t*64 + slot
            int slot = g & 63;
            int t    = (g >> 6) & 3;
            int kkl  = g >> 8;
            int nd   = t * 16 + (slot & 15);
            int c8   = (kkl << 2) | (slot >> 4);
            half8 v;
#pragma unroll
            for (int i = 0; i < 8; ++i) v[i] = (_Float16)tile[c8 * 8 + i][nd];
            *(half8*)(dst + ((size_t)ch * 1024 + g) * 8) = v;
        }
        __syncthreads();
    }
}

// --------- K2: merged a/b marginals from fragment-order fp16 ----------------
// raw_dot = nrm * <fp16 normalized vec, pooled vec> + mu * S(pooled vec)
__global__ void __launch_bounds__(256)
marg_kernel(const _Float16* __restrict__ Uht, const _Float16* __restrict__ Vht,
            const float* __restrict__ BpT, const float* __restrict__ QpT,
            const float* __restrict__ muA, const float* __restrict__ nrmA,
            const float* __restrict__ Ssc,
            float* __restrict__ a_out, float* __restrict__ b_out) {
    __shared__ __align__(16) float WL[512 * 32];   // [c][k] 64 KB
    __shared__ float Sl[32];
    int lane = threadIdx.x & 63;   // node
    int kq   = threadIdx.x >> 6;   // k = kq*8 .. +7

    const _Float16* src16;
    float mu, nrm;
    if (blockIdx.x < 256) {
        // a-marginals: block per q (XCD-grouped), k enumerates w (32)
        int q = (blockIdx.x & 7) * 32 + (blockIdx.x >> 3);
        for (int t = threadIdx.x; t < 4096; t += 256)
            ((float4*)WL)[t] = ((const float4*)BpT)[t];
        if (threadIdx.x < 32) Sl[threadIdx.x] = Ssc[threadIdx.x];  // S_w
        src16 = Uht + (size_t)q * 32768;
        mu  = muA[(32 + q) * 64 + lane];
        nrm = nrmA[(32 + q) * 64 + lane];
    } else {
        // b-marginals: block per (w, q-group of 32), k enumerates qlocal
        int id = blockIdx.x - 256;
        int w = id >> 3, qg = id & 7;
        for (int t = threadIdx.x; t < 4096; t += 256) {
            int c = t >> 3, k = t & 7;
            ((float4*)WL)[t] = ((const float4*)(QpT + (size_t)c * 256 + qg * 32))[k];
        }
        if (threadIdx.x < 32) Sl[threadIdx.x] = Ssc[32 + qg * 32 + threadIdx.x]; // S'_q
        src16 = Vht + (size_t)w * 32768;
        mu  = muA[w * 64 + lane];
        nrm = nrmA[w * 64 + lane];
    }
    __syncthreads();

    // lane's node-n data: chunk (kk, t=n>>4, slot=(hi<<4)|(n&15)) = c kk*32+hi*8..+8
    int lbase = (lane >> 4) * 64 + (lane & 15);
    float acc[8] = {0, 0, 0, 0, 0, 0, 0, 0};
#pragma unroll 1
    for (int kk = 0; kk < 16; ++kk) {
#pragma unroll
        for (int hi = 0; hi < 4; ++hi) {
            half8 x8 = *(const half8*)(src16 +
                        ((size_t)(kk * 256 + lbase + (hi << 4)) * 8));
            int cb = kk * 32 + hi * 8;
#pragma unroll
            for (int j = 0; j < 8; ++j) {
                float xv = (float)x8[j];
                const float* wl = WL + (cb + j) * 32 + kq * 8;
                float4 b0 = *(const float4*)wl;
                float4 b1 = *(const float4*)(wl + 4);
                acc[0] = fmaf(xv, b0.x, acc[0]); acc[1] = fmaf(xv, b0.y, acc[1]);
                acc[2] = fmaf(xv, b0.z, acc[2]); acc[3] = fmaf(xv, b0.w, acc[3]);
                acc[4] = fmaf(xv, b1.x, acc[4]); acc[5] = fmaf(xv, b1.y, acc[5]);
                acc[6] = fmaf(xv, b1.z, acc[6]); acc[7] = fmaf(xv, b1.w, acc[7]);
            }
        }
    }
#pragma unroll
    for (int k = 0; k < 8; ++k) {
        float raw = fmaf(mu, Sl[kq * 8 + k], nrm * acc[k]);
        float v = fmaxf(raw, 0.0f) + 0.001f;
        v += 1e-5f;
        float s = v;
        s += __shfl_xor(s, 1);  s += __shfl_xor(s, 2);  s += __shfl_xor(s, 4);
        s += __shfl_xor(s, 8);  s += __shfl_xor(s, 16); s += __shfl_xor(s, 32);
        v = v * (64.0f / s);
        if (blockIdx.x < 256) {
            int q = (blockIdx.x & 7) * 32 + (blockIdx.x >> 3), w = kq * 8 + k;
            a_out[((size_t)q * 32 + w) * 64 + lane] = v;
        } else {
            int id = blockIdx.x - 256;
            int w = id >> 3, q = (id & 7) * 32 + kq * 8 + k;
            b_out[((size_t)w * 256 + q) * 64 + lane] = v;
        }
    }
}

// --------- K3: MFMA sim (fragment loads) -> fp16 Gibbs tiles ----------------
// XCD-resident: blockIdx%8 = XCD handles one q-group. Loads lane-contiguous.
__global__ void __launch_bounds__(256, 4)
sim_kernel(const _Float16* __restrict__ Uht, const _Float16* __restrict__ Vht,
           _Float16* __restrict__ Mg, float* __restrict__ s0A,
           int q0, int qchunk) {
    __shared__ __align__(16) float T[2][64 * LDP];   // 34.8 KB

    int x    = blockIdx.x & 7;
    int i    = blockIdx.x >> 3;
    int w    = i & 31;
    int wave = threadIdx.x >> 6;
    int lane = threadIdx.x & 63;
    int q    = q0 + (x * (qchunk >> 5) + (i >> 5)) * 4 + wave;
    int lo16 = lane & 15;
    int hi4  = lane >> 4;
    int ig   = lane >> 3;
    int jg   = lane & 7;

    floatx4 acc[4][4];
#pragma unroll
    for (int tm = 0; tm < 4; ++tm)
#pragma unroll
        for (int tn = 0; tn < 4; ++tn)
            acc[tm][tn] = (floatx4){0.f, 0.f, 0.f, 0.f};

    const _Float16* Abase = Uht + (size_t)q * 32768 + lane * 8;
    const _Float16* Bbase = Vht + (size_t)w * 32768 + lane * 8;
#pragma unroll 1
    for (int kk = 0; kk < 16; ++kk) {
        half8 bf[4];
#pragma unroll
        for (int t = 0; t < 4; ++t)
            bf[t] = *(const half8*)(Bbase + (size_t)(kk * 4 + t) * 512);
#pragma unroll
        for (int tm = 0; tm < 4; ++tm) {
            half8 af = *(const half8*)(Abase + (size_t)(kk * 4 + tm) * 512);
#pragma unroll
            for (int tn = 0; tn < 4; ++tn)
                acc[tm][tn] = __builtin_amdgcn_mfma_f32_16x16x32_f16(
                    af, bf[tn], acc[tm][tn], 0, 0, 0);
        }
    }

    // wave-uniform tile max for the fp16 rescale
    float lmax = -2.0f;
#pragma unroll
    for (int tm = 0; tm < 4; ++tm)
#pragma unroll
        for (int tn = 0; tn < 4; ++tn)
#pragma unroll
            for (int r = 0; r < 4; ++r) lmax = fmaxf(lmax, acc[tm][tn][r]);
    lmax = fmaxf(lmax, __shfl_xor(lmax, 1));
    lmax = fmaxf(lmax, __shfl_xor(lmax, 2));
    lmax = fmaxf(lmax, __shfl_xor(lmax, 4));
    lmax = fmaxf(lmax, __shfl_xor(lmax, 8));
    lmax = fmaxf(lmax, __shfl_xor(lmax, 16));
    lmax = fmaxf(lmax, __shfl_xor(lmax, 32));
    float s0 = lmax;

    // exp + LDS roundtrip into the xor-permuted (ig,jg) layout, fp16 on read
    half8 Mh[8];
#pragma unroll 1
    for (int round = 0; round < 2; ++round) {
        if ((wave >> 1) == round) {
            float* buf = T[wave & 1];
#pragma unroll
            for (int tm = 0; tm < 4; ++tm)
#pragma unroll
                for (int tn = 0; tn < 4; ++tn)
#pragma unroll
                    for (int r = 0; r < 4; ++r) {
                        int row = tm * 16 + hi4 * 4 + r;
                        int col = tn * 16 + lo16;
                        int sp  = (col & 7) ^ (row >> 3);
                        buf[row * LDP + (col & ~7) + sp] =
                            fexp2((acc[tm][tn][r] - s0) * K_SIM2M);
                    }
        }
        __syncthreads();
        if ((wave >> 1) == round) {
            const float* buf = T[wave & 1];
#pragma unroll
            for (int t = 0; t < 8; ++t) {
                const float* p = buf + (ig * 8 + (jg ^ t)) * LDP + jg * 8;
                float4 m0 = *(const float4*)p;
                float4 m1 = *(const float4*)(p + 4);
                half8 h;
                h[0] = (_Float16)m0.x; h[1] = (_Float16)m0.y;
                h[2] = (_Float16)m0.z; h[3] = (_Float16)m0.w;
                h[4] = (_Float16)m1.x; h[5] = (_Float16)m1.y;
                h[6] = (_Float16)m1.z; h[7] = (_Float16)m1.w;
                Mh[t] = h;
            }
        }
        __syncthreads();
    }

    int p_loc = (q - q0) * 32 + w;
    _Float16* mp = Mg + (size_t)p_loc * 4096 + lane * 8;
#pragma unroll
    for (int t = 0; t < 8; ++t) *(half8*)(mp + (size_t)t * 512) = Mh[t];
    if (lane == 0) s0A[q * 32 + w] = s0;
}

// --------- K4: Sinkhorn + logits. 4 pair-waves per block, 4 waves/EU --------
// (256,4): 128-reg budget -- this loop compiles ~64 VGPR clean (R4/R9).
__global__ void __launch_bounds__(256, 4)
skh_kernel(const _Float16* __restrict__ Mg, const float* __restrict__ s0A,
           const float* __restrict__ a_arr, const float* __restrict__ b_arr,
           float* __restrict__ out, int q0) {
    int wave  = threadIdx.x >> 6;
    int lane  = threadIdx.x & 63;
    int p_loc = blockIdx.x * 4 + wave;
    int q  = q0 + (p_loc >> 5);
    int w  = p_loc & 31;
    int gp = q * 32 + w;
    int ig = lane >> 3;
    int jg = lane & 7;

    const _Float16* mp = Mg + (size_t)p_loc * 4096 + lane * 8;
    half8 Mh[8];
#pragma unroll
    for (int t = 0; t < 8; ++t) Mh[t] = *(const half8*)(mp + (size_t)t * 512);

    float a_own = a_arr[(size_t)gp * 64 + ig * 8 + jg];
    float b_own = b_arr[((size_t)w * 256 + q) * 64 + jg * 8 + ig];

    float wvp[8];
#pragma unroll
    for (int s = 0; s < 8; ++s) wvp[s] = 1.0f;
    float q8[8];
    float w_prev = -1.f;

#pragma unroll 1
    for (int it = 0; it < 100; ++it) {
        float p[8];
#pragma unroll
        for (int t = 0; t < 8; ++t) {
            float s = (float)Mh[t][0] * wvp[0];
#pragma unroll
            for (int c = 1; c < 8; ++c) s = fmaf((float)Mh[t][c], wvp[c], s);
            p[t] = s;
        }
        p[0] += __shfl_xor(p[4], 4); p[1] += __shfl_xor(p[5], 4);
        p[2] += __shfl_xor(p[6], 4); p[3] += __shfl_xor(p[7], 4);
        p[0] += __shfl_xor(p[2], 2); p[1] += __shfl_xor(p[3], 2);
        p[0] += __shfl_xor(p[1], 1);
        float z_own = a_own * fast_rcp(p[0]);
        q8[0] = z_own;
        q8[1] = __shfl_xor(q8[0], 1);
        q8[2] = __shfl_xor(q8[0], 2); q8[3] = __shfl_xor(q8[1], 2);
        q8[4] = __shfl_xor(q8[0], 4); q8[5] = __shfl_xor(q8[1], 4);
        q8[6] = __shfl_xor(q8[2], 4); q8[7] = __shfl_xor(q8[3], 4);
        float cp[8];
#pragma unroll
        for (int s = 0; s < 8; ++s) {
            float v = (float)Mh[0][s] * q8[0];
#pragma unroll
            for (int t = 1; t < 8; ++t) v = fmaf((float)Mh[t][s], q8[t], v);
            cp[s] = v;
        }
        cp[0] += __shfl_xor(cp[4], 32); cp[1] += __shfl_xor(cp[5], 32);
        cp[2] += __shfl_xor(cp[6], 32); cp[3] += __shfl_xor(cp[7], 32);
        cp[0] += __shfl_xor(cp[2], 16); cp[1] += __shfl_xor(cp[3], 16);
        cp[0] += __shfl_xor(cp[1], 8);
        float w_own = b_own * fast_rcp(cp[0]);
        wvp[0] = w_own;
        wvp[1] = __shfl_xor(wvp[0], 8);
        wvp[2] = __shfl_xor(wvp[0], 16); wvp[3] = __shfl_xor(wvp[1], 16);
        wvp[4] = __shfl_xor(wvp[0], 32); wvp[5] = __shfl_xor(wvp[1], 32);
        wvp[6] = __shfl_xor(wvp[2], 32); wvp[7] = __shfl_xor(wvp[3], 32);
        // w stable across all 64 cols -> next z,w identical -> fixed point
        bool same = fabsf(w_own - w_prev) <= 1e-5f * w_own;
        w_prev = w_own;
        if (__all(same)) break;
    }

    float s0 = s0A[gp];
    float s = 0.f;
#pragma unroll
    for (int t = 0; t < 8; ++t)
#pragma unroll
        for (int c = 0; c < 8; ++c) {
            float m    = fmaxf((float)Mh[t][c], 1e-30f);
            float sim  = fmaf(flog2(m), K_M2SIM, s0);
            float flow = q8[t] * m * wvp[c];
            s = fmaf(sim, flow, s);
        }
    s += __shfl_xor(s, 1);  s += __shfl_xor(s, 2);  s += __shfl_xor(s, 4);
    s += __shfl_xor(s, 8);  s += __shfl_xor(s, 16); s += __shfl_xor(s, 32);
    if (lane == 0) out[gp] = s * 0.1953125f;   // 12.5/64
}

// ---------------------------------------------------------------------------
extern "C" void kernel_launch(void* const* d_in, const int* in_sizes, int n_in,
                              void* d_out, int out_size, void* d_ws, size_t ws_size,
                              hipStream_t stream) {
    (void)in_sizes; (void)n_in; (void)out_size;
    const float* support = (const float*)d_in[0];   // 32*512*64
    const float* query   = (const float*)d_in[1];   // 256*512*64

    char* ws = (char*)d_ws;
    _Float16* Uht = (_Float16*)ws;                  // 16 MB (fragment order)
    _Float16* Vht = Uht + 8388608;                  //  2 MB (fragment order)
    float* BpT  = (float*)(Vht + 1048576);          // 64 KB  [512][32]
    float* QpT  = BpT + 16384;                      // 512 KB [512][256]
    float* aA   = QpT + 131072;                     //  2 MB
    float* bA   = aA + 524288;                      //  2 MB
    float* s0A  = bA + 524288;                      // 32 KB
    float* muA  = s0A + 8192;                       // 72 KB [288][64]
    float* nrmA = muA + 18432;                      // 72 KB
    float* Ssc  = nrmA + 18432;                     // ~1 KB [288]
    _Float16* Mg = (_Float16*)(Ssc + 288);          // up to 64 MB
    size_t base = (size_t)((char*)Mg - ws);

    int nsplit = 1;                                 // adaptive to ws_size
    if (ws_size < base + (size_t)64 * 1024 * 1024) nsplit = 2;
    if (ws_size < base + (size_t)32 * 1024 * 1024) nsplit = 4;

    norm_kernel<<<288, 1024, 0, stream>>>(support, query, Vht, Uht, BpT, QpT,
                                          muA, nrmA, Ssc);
    marg_kernel<<<512, 256, 0, stream>>>(Uht, Vht, BpT, QpT, muA, nrmA, Ssc,
                                         aA, bA);
    int qchunk = 256 / nsplit;
    for (int s = 0; s < nsplit; ++s) {
        sim_kernel<<<qchunk * 8, 256, 0, stream>>>(Uht, Vht, Mg, s0A,
                                                   s * qchunk, qchunk);
        skh_kernel<<<qchunk * 8, 256, 0, stream>>>(Mg, s0A, aA, bA,
                                                   (float*)d_out, s * qchunk);
    }
}

// Round 11
// 183.671 us; speedup vs baseline: 2.8466x; 1.1123x over previous
//
#include <hip/hip_runtime.h>
#include <math.h>

// ---------------------------------------------------------------------------
// EMD layer (Sinkhorn-OT logits) for MI355X.
// support: [32,512,8,8] f32, query: [256,512,8,8] f32 -> logits [256,32] f32.
//
// R11: sim+skh re-fused. Since R9 both run at (256,4)=16 waves/CU, so the
//      split's only job was the 128MB Mg round-trip + an extra launch.
//      R4 evidence: fused sim+Sinkhorn at (256,4) compiles clean (no spill)
//      and cross-block wave overlap (m114) hides the Sinkhorn VALU phase
//      behind other blocks' MFMA phases. Output bit-identical to R10.
//      norm (R10 1024-thread) and marg unchanged.
// ---------------------------------------------------------------------------

#define DEV static __device__ __forceinline__

typedef _Float16 half8 __attribute__((ext_vector_type(8)));
typedef float floatx4 __attribute__((ext_vector_type(4)));

DEV float fast_rcp(float x) {
#if __has_builtin(__builtin_amdgcn_rcpf)
    return __builtin_amdgcn_rcpf(x);
#else
    return 1.0f / x;
#endif
}
DEV float fexp2(float x) {
#if __has_builtin(__builtin_amdgcn_exp2f)
    return __builtin_amdgcn_exp2f(x);
#else
    return exp2f(x);
#endif
}
DEV float flog2(float x) {
#if __has_builtin(__builtin_amdgcn_logf)
    return __builtin_amdgcn_logf(x);
#else
    return log2f(x);
#endif
}

#define K_SIM2M 28.853900817779268f    // 20/ln2 : M = 2^((sim-1)*K_SIM2M)
#define K_M2SIM 0.034657359027997264f  // 0.05*ln2 : sim = 1 + log2(M)*K_M2SIM
#define LDP 68                         // padded LDS row stride (floats)

// ------ K1: center+normalize over C -> fp16 FRAGMENT order, + pool stats ----
// 1024 threads: 16 waves. Fragment chunk (kk,t,slot) = channels
// kk*32+(slot>>4)*8..+8 of node t*16+(slot&15), at ((kk*4+t)*64+slot)*8 halves.
__global__ void __launch_bounds__(1024, 1)
norm_kernel(const float* __restrict__ support, const float* __restrict__ query,
            _Float16* __restrict__ Vht, _Float16* __restrict__ Uht,
            float* __restrict__ BpT, float* __restrict__ QpT,
            float* __restrict__ muA, float* __restrict__ nrmA,
            float* __restrict__ Ssc) {
    __shared__ float red1[16][64];
    __shared__ float red2[16][64];
    __shared__ float muL[64], invL[64];
    __shared__ float tile[128][65];

    int sid = blockIdx.x;             // 0..287
    const float* src;
    _Float16* dst;
    float* poolT;
    int pstride, pidx;
    if (sid < 32) {
        src = support + (size_t)sid * 32768; dst = Vht + (size_t)sid * 32768;
        poolT = BpT; pstride = 32; pidx = sid;
    } else {
        src = query + (size_t)(sid - 32) * 32768; dst = Uht + (size_t)(sid - 32) * 32768;
        poolT = QpT; pstride = 256; pidx = sid - 32;
    }

    int node = threadIdx.x & 63;
    int cq   = threadIdx.x >> 6;      // wave index 0..15

    // ---- stats pass: each wave handles 32 channels ----
    float s1 = 0.f, s2 = 0.f;
#pragma unroll 8
    for (int j = 0; j < 32; ++j) {
        int c = cq * 32 + j;
        float x = src[c * 64 + node];
        s1 += x; s2 += x * x;
        float ps = x;                  // pool: sum over the wave's 64 nodes
        ps += __shfl_xor(ps, 1);  ps += __shfl_xor(ps, 2);  ps += __shfl_xor(ps, 4);
        ps += __shfl_xor(ps, 8);  ps += __shfl_xor(ps, 16); ps += __shfl_xor(ps, 32);
        if (node == 0) poolT[(size_t)c * pstride + pidx] = ps * (1.0f / 64.0f);
    }
    red1[cq][node] = s1;
    red2[cq][node] = s2;
    __syncthreads();
    if (threadIdx.x < 64) {
        float t1 = 0.f, t2 = 0.f;
#pragma unroll
        for (int k = 0; k < 16; ++k) { t1 += red1[k][node]; t2 += red2[k][node]; }
        float mu  = t1 * (1.0f / 512.0f);
        float ss  = t2 - 512.0f * mu * mu;
        float nrm = fmaxf(sqrtf(fmaxf(ss, 0.0f)), 1e-8f);
        muL[node]  = mu;
        invL[node] = 1.0f / nrm;
        muA[sid * 64 + node]  = mu;
        nrmA[sid * 64 + node] = nrm;
        float sS = t1;                 // S = sum_c pool[c]
        sS += __shfl_xor(sS, 1);  sS += __shfl_xor(sS, 2);  sS += __shfl_xor(sS, 4);
        sS += __shfl_xor(sS, 8);  sS += __shfl_xor(sS, 16); sS += __shfl_xor(sS, 32);
        if (node == 0) Ssc[sid] = sS * (1.0f / 64.0f);
    }
    __syncthreads();

    // ---- normalize + fragment-order write, slab = 128 channels ----
    float mu = muL[node], inv = invL[node];
    for (int ch = 0; ch < 4; ++ch) {
#pragma unroll
        for (int j = 0; j < 8; ++j) {
            int cl = cq * 8 + j;       // 16 waves x 8 = 128 channels
            float x = src[(ch * 128 + cl) * 64 + node];
            tile[cl][node] = (x - mu) * inv;
        }
        __syncthreads();
        // 1024 fragment chunks per slab: exactly one per thread
        {
            int g    = threadIdx.x;    // kkl*256 + t*64 + slot
            int slot = g & 63;
            int t    = (g >> 6) & 3;
            int kkl  = g >> 8;
            int nd   = t * 16 + (slot & 15);
            int c8   = (kkl << 2) | (slot >> 4);
            half8 v;
#pragma unroll
            for (int i = 0; i < 8; ++i) v[i] = (_Float16)tile[c8 * 8 + i][nd];
            *(half8*)(dst + ((size_t)ch * 1024 + g) * 8) = v;
        }
        __syncthreads();
    }
}

// --------- K2: merged a/b marginals from fragment-order fp16 ----------------
// raw_dot = nrm * <fp16 normalized vec, pooled vec> + mu * S(pooled vec)
__global__ void __launch_bounds__(256)
marg_kernel(const _Float16* __restrict__ Uht, const _Float16* __restrict__ Vht,
            const float* __restrict__ BpT, const float* __restrict__ QpT,
            const float* __restrict__ muA, const float* __restrict__ nrmA,
            const float* __restrict__ Ssc,
            float* __restrict__ a_out, float* __restrict__ b_out) {
    __shared__ __align__(16) float WL[512 * 32];   // [c][k] 64 KB
    __shared__ float Sl[32];
    int lane = threadIdx.x & 63;   // node
    int kq   = threadIdx.x >> 6;   // k = kq*8 .. +7

    const _Float16* src16;
    float mu, nrm;
    if (blockIdx.x < 256) {
        // a-marginals: block per q (XCD-grouped), k enumerates w (32)
        int q = (blockIdx.x & 7) * 32 + (blockIdx.x >> 3);
        for (int t = threadIdx.x; t < 4096; t += 256)
            ((float4*)WL)[t] = ((const float4*)BpT)[t];
        if (threadIdx.x < 32) Sl[threadIdx.x] = Ssc[threadIdx.x];  // S_w
        src16 = Uht + (size_t)q * 32768;
        mu  = muA[(32 + q) * 64 + lane];
        nrm = nrmA[(32 + q) * 64 + lane];
    } else {
        // b-marginals: block per (w, q-group of 32), k enumerates qlocal
        int id = blockIdx.x - 256;
        int w = id >> 3, qg = id & 7;
        for (int t = threadIdx.x; t < 4096; t += 256) {
            int c = t >> 3, k = t & 7;
            ((float4*)WL)[t] = ((const float4*)(QpT + (size_t)c * 256 + qg * 32))[k];
        }
        if (threadIdx.x < 32) Sl[threadIdx.x] = Ssc[32 + qg * 32 + threadIdx.x]; // S'_q
        src16 = Vht + (size_t)w * 32768;
        mu  = muA[w * 64 + lane];
        nrm = nrmA[w * 64 + lane];
    }
    __syncthreads();

    // lane's node-n data: chunk (kk, t=n>>4, slot=(hi<<4)|(n&15)) = c kk*32+hi*8..+8
    int lbase = (lane >> 4) * 64 + (lane & 15);
    float acc[8] = {0, 0, 0, 0, 0, 0, 0, 0};
#pragma unroll 1
    for (int kk = 0; kk < 16; ++kk) {
#pragma unroll
        for (int hi = 0; hi < 4; ++hi) {
            half8 x8 = *(const half8*)(src16 +
                        ((size_t)(kk * 256 + lbase + (hi << 4)) * 8));
            int cb = kk * 32 + hi * 8;
#pragma unroll
            for (int j = 0; j < 8; ++j) {
                float xv = (float)x8[j];
                const float* wl = WL + (cb + j) * 32 + kq * 8;
                float4 b0 = *(const float4*)wl;
                float4 b1 = *(const float4*)(wl + 4);
                acc[0] = fmaf(xv, b0.x, acc[0]); acc[1] = fmaf(xv, b0.y, acc[1]);
                acc[2] = fmaf(xv, b0.z, acc[2]); acc[3] = fmaf(xv, b0.w, acc[3]);
                acc[4] = fmaf(xv, b1.x, acc[4]); acc[5] = fmaf(xv, b1.y, acc[5]);
                acc[6] = fmaf(xv, b1.z, acc[6]); acc[7] = fmaf(xv, b1.w, acc[7]);
            }
        }
    }
#pragma unroll
    for (int k = 0; k < 8; ++k) {
        float raw = fmaf(mu, Sl[kq * 8 + k], nrm * acc[k]);
        float v = fmaxf(raw, 0.0f) + 0.001f;
        v += 1e-5f;
        float s = v;
        s += __shfl_xor(s, 1);  s += __shfl_xor(s, 2);  s += __shfl_xor(s, 4);
        s += __shfl_xor(s, 8);  s += __shfl_xor(s, 16); s += __shfl_xor(s, 32);
        v = v * (64.0f / s);
        if (blockIdx.x < 256) {
            int q = (blockIdx.x & 7) * 32 + (blockIdx.x >> 3), w = kq * 8 + k;
            a_out[((size_t)q * 32 + w) * 64 + lane] = v;
        } else {
            int id = blockIdx.x - 256;
            int w = id >> 3, q = (id & 7) * 32 + kq * 8 + k;
            b_out[((size_t)w * 256 + q) * 64 + lane] = v;
        }
    }
}

// --------- K3: FUSED MFMA sim + exp/transpose + Sinkhorn + logits -----------
// Wave per (q,w). XCD-resident: blockIdx%8 = XCD handles one q-group.
// Phase 1-2 = R10 sim (fragment loads); phase 3-4 = R10 skh (Mh in-register).
__global__ void __launch_bounds__(256, 4)
emd_kernel(const _Float16* __restrict__ Uht, const _Float16* __restrict__ Vht,
           const float* __restrict__ a_arr, const float* __restrict__ b_arr,
           float* __restrict__ out) {
    __shared__ __align__(16) float T[2][64 * LDP];   // 34.8 KB

    int x    = blockIdx.x & 7;
    int i    = blockIdx.x >> 3;
    int w    = i & 31;
    int wave = threadIdx.x >> 6;
    int lane = threadIdx.x & 63;
    int q    = (x * 8 + (i >> 5)) * 4 + wave;        // XCD x: q in [32x,32x+32)
    int lo16 = lane & 15;
    int hi4  = lane >> 4;
    int ig   = lane >> 3;
    int jg   = lane & 7;

    // ---- phase 1: sim tile via fp16 MFMA, fragment-order loads ----
    floatx4 acc[4][4];
#pragma unroll
    for (int tm = 0; tm < 4; ++tm)
#pragma unroll
        for (int tn = 0; tn < 4; ++tn)
            acc[tm][tn] = (floatx4){0.f, 0.f, 0.f, 0.f};

    const _Float16* Abase = Uht + (size_t)q * 32768 + lane * 8;
    const _Float16* Bbase = Vht + (size_t)w * 32768 + lane * 8;
#pragma unroll 1
    for (int kk = 0; kk < 16; ++kk) {
        half8 bf[4];
#pragma unroll
        for (int t = 0; t < 4; ++t)
            bf[t] = *(const half8*)(Bbase + (size_t)(kk * 4 + t) * 512);
#pragma unroll
        for (int tm = 0; tm < 4; ++tm) {
            half8 af = *(const half8*)(Abase + (size_t)(kk * 4 + tm) * 512);
#pragma unroll
            for (int tn = 0; tn < 4; ++tn)
                acc[tm][tn] = __builtin_amdgcn_mfma_f32_16x16x32_f16(
                    af, bf[tn], acc[tm][tn], 0, 0, 0);
        }
    }

    // ---- wave-uniform tile max for the fp16 rescale ----
    float lmax = -2.0f;
#pragma unroll
    for (int tm = 0; tm < 4; ++tm)
#pragma unroll
        for (int tn = 0; tn < 4; ++tn)
#pragma unroll
            for (int r = 0; r < 4; ++r) lmax = fmaxf(lmax, acc[tm][tn][r]);
    lmax = fmaxf(lmax, __shfl_xor(lmax, 1));
    lmax = fmaxf(lmax, __shfl_xor(lmax, 2));
    lmax = fmaxf(lmax, __shfl_xor(lmax, 4));
    lmax = fmaxf(lmax, __shfl_xor(lmax, 8));
    lmax = fmaxf(lmax, __shfl_xor(lmax, 16));
    lmax = fmaxf(lmax, __shfl_xor(lmax, 32));
    float s0 = lmax;

    // ---- phase 2: exp + LDS roundtrip into xor-permuted layout, fp16 ----
    half8 Mh[8];
#pragma unroll 1
    for (int round = 0; round < 2; ++round) {
        if ((wave >> 1) == round) {
            float* buf = T[wave & 1];
#pragma unroll
            for (int tm = 0; tm < 4; ++tm)
#pragma unroll
                for (int tn = 0; tn < 4; ++tn)
#pragma unroll
                    for (int r = 0; r < 4; ++r) {
                        int row = tm * 16 + hi4 * 4 + r;
                        int col = tn * 16 + lo16;
                        int sp  = (col & 7) ^ (row >> 3);
                        buf[row * LDP + (col & ~7) + sp] =
                            fexp2((acc[tm][tn][r] - s0) * K_SIM2M);
                    }
        }
        __syncthreads();
        if ((wave >> 1) == round) {
            const float* buf = T[wave & 1];
#pragma unroll
            for (int t = 0; t < 8; ++t) {
                const float* p = buf + (ig * 8 + (jg ^ t)) * LDP + jg * 8;
                float4 m0 = *(const float4*)p;
                float4 m1 = *(const float4*)(p + 4);
                half8 h;
                h[0] = (_Float16)m0.x; h[1] = (_Float16)m0.y;
                h[2] = (_Float16)m0.z; h[3] = (_Float16)m0.w;
                h[4] = (_Float16)m1.x; h[5] = (_Float16)m1.y;
                h[6] = (_Float16)m1.z; h[7] = (_Float16)m1.w;
                Mh[t] = h;
            }
        }
        __syncthreads();
    }

    // ---- phase 3: Sinkhorn, reduce-scatter + all-gather, tol early exit ----
    int gp = q * 32 + w;
    float a_own = a_arr[(size_t)gp * 64 + ig * 8 + jg];
    float b_own = b_arr[((size_t)w * 256 + q) * 64 + jg * 8 + ig];

    float wvp[8];
#pragma unroll
    for (int s = 0; s < 8; ++s) wvp[s] = 1.0f;
    float q8[8];
    float w_prev = -1.f;

#pragma unroll 1
    for (int it = 0; it < 100; ++it) {
        float p[8];
#pragma unroll
        for (int t = 0; t < 8; ++t) {
            float s = (float)Mh[t][0] * wvp[0];
#pragma unroll
            for (int c = 1; c < 8; ++c) s = fmaf((float)Mh[t][c], wvp[c], s);
            p[t] = s;
        }
        p[0] += __shfl_xor(p[4], 4); p[1] += __shfl_xor(p[5], 4);
        p[2] += __shfl_xor(p[6], 4); p[3] += __shfl_xor(p[7], 4);
        p[0] += __shfl_xor(p[2], 2); p[1] += __shfl_xor(p[3], 2);
        p[0] += __shfl_xor(p[1], 1);
        float z_own = a_own * fast_rcp(p[0]);
        q8[0] = z_own;
        q8[1] = __shfl_xor(q8[0], 1);
        q8[2] = __shfl_xor(q8[0], 2); q8[3] = __shfl_xor(q8[1], 2);
        q8[4] = __shfl_xor(q8[0], 4); q8[5] = __shfl_xor(q8[1], 4);
        q8[6] = __shfl_xor(q8[2], 4); q8[7] = __shfl_xor(q8[3], 4);
        float cp[8];
#pragma unroll
        for (int s = 0; s < 8; ++s) {
            float v = (float)Mh[0][s] * q8[0];
#pragma unroll
            for (int t = 1; t < 8; ++t) v = fmaf((float)Mh[t][s], q8[t], v);
            cp[s] = v;
        }
        cp[0] += __shfl_xor(cp[4], 32); cp[1] += __shfl_xor(cp[5], 32);
        cp[2] += __shfl_xor(cp[6], 32); cp[3] += __shfl_xor(cp[7], 32);
        cp[0] += __shfl_xor(cp[2], 16); cp[1] += __shfl_xor(cp[3], 16);
        cp[0] += __shfl_xor(cp[1], 8);
        float w_own = b_own * fast_rcp(cp[0]);
        wvp[0] = w_own;
        wvp[1] = __shfl_xor(wvp[0], 8);
        wvp[2] = __shfl_xor(wvp[0], 16); wvp[3] = __shfl_xor(wvp[1], 16);
        wvp[4] = __shfl_xor(wvp[0], 32); wvp[5] = __shfl_xor(wvp[1], 32);
        wvp[6] = __shfl_xor(wvp[2], 32); wvp[7] = __shfl_xor(wvp[3], 32);
        // w stable across all 64 cols -> next z,w identical -> fixed point
        bool same = fabsf(w_own - w_prev) <= 1e-5f * w_own;
        w_prev = w_own;
        if (__all(same)) break;
    }

    // ---- phase 4: logits; sim = s0 + log2(M')*eps*ln2 ----
    float s = 0.f;
#pragma unroll
    for (int t = 0; t < 8; ++t)
#pragma unroll
        for (int c = 0; c < 8; ++c) {
            float m    = fmaxf((float)Mh[t][c], 1e-30f);
            float sim  = fmaf(flog2(m), K_M2SIM, s0);
            float flow = q8[t] * m * wvp[c];
            s = fmaf(sim, flow, s);
        }
    s += __shfl_xor(s, 1);  s += __shfl_xor(s, 2);  s += __shfl_xor(s, 4);
    s += __shfl_xor(s, 8);  s += __shfl_xor(s, 16); s += __shfl_xor(s, 32);
    if (lane == 0) out[gp] = s * 0.1953125f;   // 12.5/64
}

// ---------------------------------------------------------------------------
extern "C" void kernel_launch(void* const* d_in, const int* in_sizes, int n_in,
                              void* d_out, int out_size, void* d_ws, size_t ws_size,
                              hipStream_t stream) {
    (void)in_sizes; (void)n_in; (void)out_size; (void)ws_size;
    const float* support = (const float*)d_in[0];   // 32*512*64
    const float* query   = (const float*)d_in[1];   // 256*512*64

    char* ws = (char*)d_ws;
    _Float16* Uht = (_Float16*)ws;                  // 16 MB (fragment order)
    _Float16* Vht = Uht + 8388608;                  //  2 MB (fragment order)
    float* BpT  = (float*)(Vht + 1048576);          // 64 KB  [512][32]
    float* QpT  = BpT + 16384;                      // 512 KB [512][256]
    float* aA   = QpT + 131072;                     //  2 MB
    float* bA   = aA + 524288;                      //  2 MB
    float* muA  = bA + 524288;                      // 72 KB [288][64]
    float* nrmA = muA + 18432;                      // 72 KB
    float* Ssc  = nrmA + 18432;                     // ~1 KB [288]  (~23 MB total)

    norm_kernel<<<288, 1024, 0, stream>>>(support, query, Vht, Uht, BpT, QpT,
                                          muA, nrmA, Ssc);
    marg_kernel<<<512, 256, 0, stream>>>(Uht, Vht, BpT, QpT, muA, nrmA, Ssc,
                                         aA, bA);
    emd_kernel<<<2048, 256, 0, stream>>>(Uht, Vht, aA, bA, (float*)d_out);
}